// Round 3
// baseline (3477.317 us; speedup 1.0000x reference)
//
#include <hip/hip_runtime.h>
#include <hip/hip_bf16.h>

// B=16, C=512, H=W=32 -> P=1024 pixels, 8 groups (64 ch), 8 heads (hd=64).
#define BB   16
#define CCH  512
#define PP   1024
#define NHD  8

typedef unsigned short u16;
typedef unsigned int   u32;

__device__ __forceinline__ float us2f(u16 u) {
    return __uint_as_float(((u32)u) << 16);
}
__device__ __forceinline__ u16 f2bu(float f) {
    __hip_bfloat16 h = __float2bfloat16(f);   // RNE
    return *reinterpret_cast<u16*>(&h);
}

template<bool F32>
__device__ __forceinline__ float4 ld4(const void* p, size_t i) {   // i % 4 == 0
    if (F32) return *(const float4*)((const float*)p + i);
    ushort4 u = *(const ushort4*)((const u16*)p + i);
    return make_float4(us2f(u.x), us2f(u.y), us2f(u.z), us2f(u.w));
}
template<bool F32>
__device__ __forceinline__ float ld1(const void* p, size_t i) {
    return F32 ? ((const float*)p)[i] : us2f(((const u16*)p)[i]);
}
template<bool F32>
__device__ __forceinline__ void st4(void* p, size_t i, float v0, float v1,
                                    float v2, float v3) {          // i % 4 == 0
    if (F32) {
        *(float4*)((float*)p + i) = make_float4(v0, v1, v2, v3);
    } else {
        ushort4 o;
        o.x = f2bu(v0); o.y = f2bu(v1); o.z = f2bu(v2); o.w = f2bu(v3);
        *(ushort4*)((u16*)p + i) = o;
    }
}

// ---------------------------------------------------------------------------
// Kernel 0: input-dtype detection on first 4096 u32 words of x.
// bf16 stream -> low halfword is a sane bf16 (exp in [100,145] or 0).
// f32 stream -> low halfword is mantissa noise (~82% insane).  flag=1 -> f32.
// ---------------------------------------------------------------------------
__launch_bounds__(256)
__global__ void detect_k(const u32* __restrict__ x, int* __restrict__ flag) {
    int cnt = 0;
    for (int i = threadIdx.x; i < 4096; i += 256) {
        u32 w = x[i];
        int e = (w >> 7) & 0xFF;
        if (e != 0 && (e < 100 || e > 145)) cnt++;
    }
    __shared__ int sh[256];
    sh[threadIdx.x] = cnt;
    __syncthreads();
    for (int off = 128; off > 0; off >>= 1) {
        if (threadIdx.x < off) sh[threadIdx.x] += sh[threadIdx.x + off];
        __syncthreads();
    }
    if (threadIdx.x == 0) *flag = (sh[0] > 1024) ? 1 : 0;
}

// ---------------------------------------------------------------------------
// Kernel 1: per-(batch,group) mean / rstd.  128 blocks x 256 threads.
// ---------------------------------------------------------------------------
template<bool F32>
__device__ void gn_stats_body(const void* x, float* mean, float* rstd,
                              float* sh, float* sq) {
    int bg = blockIdx.x;
    size_t base = (size_t)bg * 65536;
    float s = 0.f, ss = 0.f;
    for (int i = threadIdx.x; i < 16384; i += 256) {
        float4 v = ld4<F32>(x, base + (size_t)i * 4);
        s  += v.x + v.y + v.z + v.w;
        ss += v.x*v.x + v.y*v.y + v.z*v.z + v.w*v.w;
    }
    sh[threadIdx.x] = s; sq[threadIdx.x] = ss;
    __syncthreads();
    for (int off = 128; off > 0; off >>= 1) {
        if (threadIdx.x < off) {
            sh[threadIdx.x] += sh[threadIdx.x + off];
            sq[threadIdx.x] += sq[threadIdx.x + off];
        }
        __syncthreads();
    }
    if (threadIdx.x == 0) {
        float m   = sh[0] * (1.f / 65536.f);
        float var = sq[0] * (1.f / 65536.f) - m * m;
        mean[bg] = m;
        rstd[bg] = rsqrtf(var + 1e-5f);
    }
}

__launch_bounds__(256)
__global__ void gn_stats_k(const void* __restrict__ x, const int* __restrict__ flag,
                           float* __restrict__ mean, float* __restrict__ rstd) {
    __shared__ float sh[256], sq[256];
    if (*flag) gn_stats_body<true >(x, mean, rstd, sh, sq);
    else       gn_stats_body<false>(x, mean, rstd, sh, sq);
}

// ---------------------------------------------------------------------------
// 1x1-conv GEMM body.  out[b][m][p] = sum_c W[m][c]*act[b][c][p] + bias[m]
// (+resid).  NORM applies groupnorm to act on the fly.  64x64 tile, 256 thr,
// 4x4/thread, K-tile 16, fp32 LDS tiles (stride 68 -> 16B-aligned float4,
// 2-way bank alias = free).
// ---------------------------------------------------------------------------
template<bool NORM, bool RESID, bool F32IN, bool F32ACT, bool F32OUT>
__device__ void gemm_body(const void* W, const void* bias,
                          const void* act, size_t actBS,
                          const void* resid,
                          const float* mean, const float* rstd,
                          const void* gamma, const void* beta,
                          void* out, size_t outBS,
                          float (*As)[68], float (*Bs)[68]) {
    const int tid = threadIdx.x;
    const int p0 = blockIdx.x * 64;
    const int m0 = blockIdx.y * 64;
    const int b  = blockIdx.z;
    const int tx = tid & 15, ty = tid >> 4;
    const int ai = tid >> 2, ak0 = (tid & 3) * 4;   // A: 64 m x 16 k
    const int bk = tid >> 4, bj0 = (tid & 15) * 4;  // B: 16 k x 64 p
    float acc[4][4] = {};

    for (int k0 = 0; k0 < CCH; k0 += 16) {
        {
            float4 v = ld4<F32IN>(W, (size_t)(m0 + ai) * CCH + k0 + ak0);
            As[ak0 + 0][ai] = v.x; As[ak0 + 1][ai] = v.y;
            As[ak0 + 2][ai] = v.z; As[ak0 + 3][ai] = v.w;
        }
        {
            int c = k0 + bk;
            float4 v = ld4<F32ACT>(act, (size_t)b * actBS + (size_t)c * PP + p0 + bj0);
            if (NORM) {
                int bg = (b << 3) + (c >> 6);
                float sc = rstd[bg] * ld1<F32IN>(gamma, c);
                float sf = ld1<F32IN>(beta, c) - mean[bg] * sc;
                v.x = v.x * sc + sf; v.y = v.y * sc + sf;
                v.z = v.z * sc + sf; v.w = v.w * sc + sf;
            }
            Bs[bk][bj0 + 0] = v.x; Bs[bk][bj0 + 1] = v.y;
            Bs[bk][bj0 + 2] = v.z; Bs[bk][bj0 + 3] = v.w;
        }
        __syncthreads();
        #pragma unroll
        for (int kk = 0; kk < 16; kk++) {
            float4 a  = *(const float4*)&As[kk][ty * 4];
            float4 bb = *(const float4*)&Bs[kk][tx * 4];
            acc[0][0] += a.x * bb.x; acc[0][1] += a.x * bb.y;
            acc[0][2] += a.x * bb.z; acc[0][3] += a.x * bb.w;
            acc[1][0] += a.y * bb.x; acc[1][1] += a.y * bb.y;
            acc[1][2] += a.y * bb.z; acc[1][3] += a.y * bb.w;
            acc[2][0] += a.z * bb.x; acc[2][1] += a.z * bb.y;
            acc[2][2] += a.z * bb.z; acc[2][3] += a.z * bb.w;
            acc[3][0] += a.w * bb.x; acc[3][1] += a.w * bb.y;
            acc[3][2] += a.w * bb.z; acc[3][3] += a.w * bb.w;
        }
        __syncthreads();
    }

    #pragma unroll
    for (int r = 0; r < 4; r++) {
        int m = m0 + ty * 4 + r;
        float bs = ld1<F32IN>(bias, m);
        float v0 = acc[r][0] + bs, v1 = acc[r][1] + bs;
        float v2 = acc[r][2] + bs, v3 = acc[r][3] + bs;
        if (RESID) {
            float4 rr = ld4<F32IN>(resid, (size_t)b * CCH * PP + (size_t)m * PP + p0 + tx * 4);
            v0 += rr.x; v1 += rr.y; v2 += rr.z; v3 += rr.w;
        }
        st4<F32OUT>(out, (size_t)b * outBS + (size_t)m * PP + p0 + tx * 4, v0, v1, v2, v3);
    }
}

__launch_bounds__(256)
__global__ void gemm_qkv_k(const void* __restrict__ W, const void* __restrict__ bias,
                           const void* __restrict__ x, const int* __restrict__ flag,
                           const float* __restrict__ mean, const float* __restrict__ rstd,
                           const void* __restrict__ gamma, const void* __restrict__ beta,
                           float* __restrict__ qkv) {
    __shared__ __align__(16) float As[16][68];
    __shared__ __align__(16) float Bs[16][68];
    if (*flag)
        gemm_body<true, false, true, true, true>(W, bias, x, (size_t)CCH * PP, nullptr,
                                                 mean, rstd, gamma, beta,
                                                 qkv, (size_t)1536 * PP, As, Bs);
    else
        gemm_body<true, false, false, false, true>(W, bias, x, (size_t)CCH * PP, nullptr,
                                                   mean, rstd, gamma, beta,
                                                   qkv, (size_t)1536 * PP, As, Bs);
}

__launch_bounds__(256)
__global__ void gemm_out_k(const void* __restrict__ W, const void* __restrict__ bias,
                           const float* __restrict__ qkv,  // attn out in q-region, stride 1536*PP
                           const void* __restrict__ x, const int* __restrict__ flag,
                           void* __restrict__ out) {
    __shared__ __align__(16) float As[16][68];
    __shared__ __align__(16) float Bs[16][68];
    if (*flag)   // f32 inputs -> f32 output
        gemm_body<false, true, true, true, true>(W, bias, qkv, (size_t)1536 * PP, x,
                                                 nullptr, nullptr, nullptr, nullptr,
                                                 out, (size_t)CCH * PP, As, Bs);
    else         // bf16 inputs -> bf16 output
        gemm_body<false, true, false, true, false>(W, bias, qkv, (size_t)1536 * PP, x,
                                                   nullptr, nullptr, nullptr, nullptr,
                                                   out, (size_t)CCH * PP, As, Bs);
}

// ---------------------------------------------------------------------------
// Kernel 3: attention over f32 qkv.  Block = (b, head, 8-query tile).
// Full score rows in LDS (8x1024 fp32), two-pass softmax, PV with 64x64 V
// tiles.  qkv layout (B, 3C, P), row = h*64+d; q=[0,512) k=[512,1024)
// v=[1024,1536).  Output overwrites the q-region in place (each block reads
// its own q tile first; tiles disjoint across blocks).
// ---------------------------------------------------------------------------
__launch_bounds__(256)
__global__ void attn_k(float* __restrict__ qkv) {
    __shared__ __align__(16) float S[8][1024];   // 32 KB
    __shared__ __align__(16) float vs[64][65];   // 16.25 KB
    __shared__ __align__(16) float qst[512];
    __shared__ float rowinv[8];
    const int tid = threadIdx.x;
    const int i0 = blockIdx.x * 8;
    const int h  = blockIdx.y;
    const int b  = blockIdx.z;
    const size_t baseq = ((size_t)(b * 1536 + h * 64)) * PP;
    const size_t basek = baseq + (size_t)512 * PP;
    const size_t basev = baseq + (size_t)1024 * PP;

    // load Q tile (64 d x 8 qi)
    {
        int d = tid >> 2, q0 = (tid & 3) * 2;
        float2 u = *(const float2*)(qkv + baseq + (size_t)d * PP + i0 + q0);
        qst[(q0 + 0) * 64 + d] = u.x;
        qst[(q0 + 1) * 64 + d] = u.y;
    }
    __syncthreads();

    // phase 1: S[qi][j] = scale * q_i . k_j
    #pragma unroll 1
    for (int jj = 0; jj < 4; jj++) {
        int j = jj * 256 + tid;
        float kreg[64];
        #pragma unroll
        for (int d = 0; d < 64; d++)
            kreg[d] = qkv[basek + (size_t)d * PP + j];
        #pragma unroll
        for (int qi = 0; qi < 8; qi++) {
            float acc = 0.f;
            #pragma unroll
            for (int d0 = 0; d0 < 64; d0 += 4) {
                float4 qv = *(const float4*)&qst[qi * 64 + d0];  // uniform broadcast
                acc += qv.x * kreg[d0] + qv.y * kreg[d0 + 1]
                     + qv.z * kreg[d0 + 2] + qv.w * kreg[d0 + 3];
            }
            S[qi][j] = acc * 0.125f;
        }
    }
    __syncthreads();

    // phase 2: softmax along j (32 lanes per row)
    {
        int row = tid >> 5, l = tid & 31;
        float mx = -3.0e38f;
        for (int j = l; j < 1024; j += 32) mx = fmaxf(mx, S[row][j]);
        #pragma unroll
        for (int off = 16; off > 0; off >>= 1) mx = fmaxf(mx, __shfl_xor(mx, off, 32));
        float sum = 0.f;
        for (int j = l; j < 1024; j += 32) {
            float e = __expf(S[row][j] - mx);
            S[row][j] = e;
            sum += e;
        }
        #pragma unroll
        for (int off = 16; off > 0; off >>= 1) sum += __shfl_xor(sum, off, 32);
        if (l == 0) rowinv[row] = 1.f / sum;
    }
    __syncthreads();

    // phase 3: out[d][qi] = sum_j P[qi][j] * v[d][j]
    const int d  = tid & 63;
    const int wv = tid >> 6;
    const int qa = wv * 2, qb = wv * 2 + 1;
    float acc0 = 0.f, acc1 = 0.f;
    const int vd = tid >> 2, vc0 = (tid & 3) * 16;
    for (int j0 = 0; j0 < 1024; j0 += 64) {
        #pragma unroll
        for (int t = 0; t < 4; t++) {
            float4 u = *(const float4*)(qkv + basev + (size_t)vd * PP + j0 + vc0 + t * 4);
            vs[vd][vc0 + t * 4 + 0] = u.x; vs[vd][vc0 + t * 4 + 1] = u.y;
            vs[vd][vc0 + t * 4 + 2] = u.z; vs[vd][vc0 + t * 4 + 3] = u.w;
        }
        __syncthreads();
        #pragma unroll
        for (int jj = 0; jj < 64; jj++) {
            float vv = vs[d][jj];
            acc0 += vv * S[qa][j0 + jj];
            acc1 += vv * S[qb][j0 + jj];
        }
        __syncthreads();
    }

    // epilogue: normalize, transpose through LDS, write into q-region
    qst[d * 8 + qa] = acc0 * rowinv[qa];
    qst[d * 8 + qb] = acc1 * rowinv[qb];
    __syncthreads();
    {
        int d2 = tid >> 2, q0 = (tid & 3) * 2;
        float2 o;
        o.x = qst[d2 * 8 + q0];
        o.y = qst[d2 * 8 + q0 + 1];
        *(float2*)(qkv + ((size_t)(b * 1536 + h * 64 + d2)) * PP + i0 + q0) = o;
    }
}

// ---------------------------------------------------------------------------
extern "C" void kernel_launch(void* const* d_in, const int* in_sizes, int n_in,
                              void* d_out, int out_size, void* d_ws, size_t ws_size,
                              hipStream_t stream) {
    const void* x     = d_in[0];
    const void* gamma = d_in[1];
    const void* beta  = d_in[2];
    const void* w_qkv = d_in[3];
    const void* b_qkv = d_in[4];
    const void* w_out = d_in[5];
    const void* b_out = d_in[6];

    char* ws = (char*)d_ws;
    int*   flag = (int*)ws;                    // 4 B
    float* mean = (float*)(ws + 512);          // 128 floats
    float* rstd = (float*)(ws + 1536);         // 128 floats
    float* qkv  = (float*)(ws + 4096);         // 16*1536*1024 f32 = 96 MB

    detect_k<<<1, 256, 0, stream>>>((const u32*)x, flag);
    gn_stats_k<<<128, 256, 0, stream>>>(x, flag, mean, rstd);
    gemm_qkv_k<<<dim3(PP / 64, 1536 / 64, BB), 256, 0, stream>>>(
        w_qkv, b_qkv, x, flag, mean, rstd, gamma, beta, qkv);
    attn_k<<<dim3(PP / 8, NHD, BB), 256, 0, stream>>>(qkv);
    gemm_out_k<<<dim3(PP / 64, 512 / 64, BB), 256, 0, stream>>>(
        w_out, b_out, qkv, x, flag, d_out);
}

// Round 4
// 1167.901 us; speedup vs baseline: 2.9774x; 2.9774x over previous
//
#include <hip/hip_runtime.h>
#include <hip/hip_bf16.h>

// B=16, C=512, H=W=32 -> P=1024 pixels, 8 groups (64 ch), 8 heads (hd=64).
#define BB   16
#define CCH  512
#define PP   1024
#define NHD  8

typedef unsigned short u16;
typedef unsigned int   u32;

__device__ __forceinline__ float us2f(u16 u) {
    return __uint_as_float(((u32)u) << 16);
}
__device__ __forceinline__ u16 f2bu(float f) {
    __hip_bfloat16 h = __float2bfloat16(f);   // RNE
    return *reinterpret_cast<u16*>(&h);
}

template<bool F32>
__device__ __forceinline__ float4 ld4(const void* p, size_t i) {   // i % 4 == 0
    if (F32) return *(const float4*)((const float*)p + i);
    ushort4 u = *(const ushort4*)((const u16*)p + i);
    return make_float4(us2f(u.x), us2f(u.y), us2f(u.z), us2f(u.w));
}
template<bool F32>
__device__ __forceinline__ float ld1(const void* p, size_t i) {
    return F32 ? ((const float*)p)[i] : us2f(((const u16*)p)[i]);
}
template<bool F32>
__device__ __forceinline__ void st4(void* p, size_t i, float v0, float v1,
                                    float v2, float v3) {          // i % 4 == 0
    if (F32) {
        *(float4*)((float*)p + i) = make_float4(v0, v1, v2, v3);
    } else {
        ushort4 o;
        o.x = f2bu(v0); o.y = f2bu(v1); o.z = f2bu(v2); o.w = f2bu(v3);
        *(ushort4*)((u16*)p + i) = o;
    }
}

// ---------------------------------------------------------------------------
// Kernel 0: input-dtype detection (flag=1 -> f32 inputs).
// ---------------------------------------------------------------------------
__launch_bounds__(256)
__global__ void detect_k(const u32* __restrict__ x, int* __restrict__ flag) {
    int cnt = 0;
    for (int i = threadIdx.x; i < 4096; i += 256) {
        u32 w = x[i];
        int e = (w >> 7) & 0xFF;
        if (e != 0 && (e < 100 || e > 145)) cnt++;
    }
    __shared__ int sh[256];
    sh[threadIdx.x] = cnt;
    __syncthreads();
    for (int off = 128; off > 0; off >>= 1) {
        if (threadIdx.x < off) sh[threadIdx.x] += sh[threadIdx.x + off];
        __syncthreads();
    }
    if (threadIdx.x == 0) *flag = (sh[0] > 1024) ? 1 : 0;
}

// ---------------------------------------------------------------------------
// Kernel 1: per-(batch,group) mean / rstd.  128 blocks x 256 threads.
// ---------------------------------------------------------------------------
template<bool F32>
__device__ void gn_stats_body(const void* x, float* mean, float* rstd,
                              float* sh, float* sq) {
    int bg = blockIdx.x;
    size_t base = (size_t)bg * 65536;
    float s = 0.f, ss = 0.f;
    for (int i = threadIdx.x; i < 16384; i += 256) {
        float4 v = ld4<F32>(x, base + (size_t)i * 4);
        s  += v.x + v.y + v.z + v.w;
        ss += v.x*v.x + v.y*v.y + v.z*v.z + v.w*v.w;
    }
    sh[threadIdx.x] = s; sq[threadIdx.x] = ss;
    __syncthreads();
    for (int off = 128; off > 0; off >>= 1) {
        if (threadIdx.x < off) {
            sh[threadIdx.x] += sh[threadIdx.x + off];
            sq[threadIdx.x] += sq[threadIdx.x + off];
        }
        __syncthreads();
    }
    if (threadIdx.x == 0) {
        float m   = sh[0] * (1.f / 65536.f);
        float var = sq[0] * (1.f / 65536.f) - m * m;
        mean[bg] = m;
        rstd[bg] = rsqrtf(var + 1e-5f);
    }
}

__launch_bounds__(256)
__global__ void gn_stats_k(const void* __restrict__ x, const int* __restrict__ flag,
                           float* __restrict__ mean, float* __restrict__ rstd) {
    __shared__ float sh[256], sq[256];
    if (*flag) gn_stats_body<true >(x, mean, rstd, sh, sq);
    else       gn_stats_body<false>(x, mean, rstd, sh, sq);
}

// ---------------------------------------------------------------------------
// 1x1-conv GEMM body (unchanged from passing round 3).
// ---------------------------------------------------------------------------
template<bool NORM, bool RESID, bool F32IN, bool F32ACT, bool F32OUT>
__device__ void gemm_body(const void* W, const void* bias,
                          const void* act, size_t actBS,
                          const void* resid,
                          const float* mean, const float* rstd,
                          const void* gamma, const void* beta,
                          void* out, size_t outBS,
                          float (*As)[68], float (*Bs)[68]) {
    const int tid = threadIdx.x;
    const int p0 = blockIdx.x * 64;
    const int m0 = blockIdx.y * 64;
    const int b  = blockIdx.z;
    const int tx = tid & 15, ty = tid >> 4;
    const int ai = tid >> 2, ak0 = (tid & 3) * 4;
    const int bk = tid >> 4, bj0 = (tid & 15) * 4;
    float acc[4][4] = {};

    for (int k0 = 0; k0 < CCH; k0 += 16) {
        {
            float4 v = ld4<F32IN>(W, (size_t)(m0 + ai) * CCH + k0 + ak0);
            As[ak0 + 0][ai] = v.x; As[ak0 + 1][ai] = v.y;
            As[ak0 + 2][ai] = v.z; As[ak0 + 3][ai] = v.w;
        }
        {
            int c = k0 + bk;
            float4 v = ld4<F32ACT>(act, (size_t)b * actBS + (size_t)c * PP + p0 + bj0);
            if (NORM) {
                int bg = (b << 3) + (c >> 6);
                float sc = rstd[bg] * ld1<F32IN>(gamma, c);
                float sf = ld1<F32IN>(beta, c) - mean[bg] * sc;
                v.x = v.x * sc + sf; v.y = v.y * sc + sf;
                v.z = v.z * sc + sf; v.w = v.w * sc + sf;
            }
            Bs[bk][bj0 + 0] = v.x; Bs[bk][bj0 + 1] = v.y;
            Bs[bk][bj0 + 2] = v.z; Bs[bk][bj0 + 3] = v.w;
        }
        __syncthreads();
        #pragma unroll
        for (int kk = 0; kk < 16; kk++) {
            float4 a  = *(const float4*)&As[kk][ty * 4];
            float4 bb = *(const float4*)&Bs[kk][tx * 4];
            acc[0][0] += a.x * bb.x; acc[0][1] += a.x * bb.y;
            acc[0][2] += a.x * bb.z; acc[0][3] += a.x * bb.w;
            acc[1][0] += a.y * bb.x; acc[1][1] += a.y * bb.y;
            acc[1][2] += a.y * bb.z; acc[1][3] += a.y * bb.w;
            acc[2][0] += a.z * bb.x; acc[2][1] += a.z * bb.y;
            acc[2][2] += a.z * bb.z; acc[2][3] += a.z * bb.w;
            acc[3][0] += a.w * bb.x; acc[3][1] += a.w * bb.y;
            acc[3][2] += a.w * bb.z; acc[3][3] += a.w * bb.w;
        }
        __syncthreads();
    }

    #pragma unroll
    for (int r = 0; r < 4; r++) {
        int m = m0 + ty * 4 + r;
        float bs = ld1<F32IN>(bias, m);
        float v0 = acc[r][0] + bs, v1 = acc[r][1] + bs;
        float v2 = acc[r][2] + bs, v3 = acc[r][3] + bs;
        if (RESID) {
            float4 rr = ld4<F32IN>(resid, (size_t)b * CCH * PP + (size_t)m * PP + p0 + tx * 4);
            v0 += rr.x; v1 += rr.y; v2 += rr.z; v3 += rr.w;
        }
        st4<F32OUT>(out, (size_t)b * outBS + (size_t)m * PP + p0 + tx * 4, v0, v1, v2, v3);
    }
}

__launch_bounds__(256)
__global__ void gemm_qkv_k(const void* __restrict__ W, const void* __restrict__ bias,
                           const void* __restrict__ x, const int* __restrict__ flag,
                           const float* __restrict__ mean, const float* __restrict__ rstd,
                           const void* __restrict__ gamma, const void* __restrict__ beta,
                           float* __restrict__ qkv) {
    __shared__ __align__(16) float As[16][68];
    __shared__ __align__(16) float Bs[16][68];
    if (*flag)
        gemm_body<true, false, true, true, true>(W, bias, x, (size_t)CCH * PP, nullptr,
                                                 mean, rstd, gamma, beta,
                                                 qkv, (size_t)1536 * PP, As, Bs);
    else
        gemm_body<true, false, false, false, true>(W, bias, x, (size_t)CCH * PP, nullptr,
                                                   mean, rstd, gamma, beta,
                                                   qkv, (size_t)1536 * PP, As, Bs);
}

__launch_bounds__(256)
__global__ void gemm_out_k(const void* __restrict__ W, const void* __restrict__ bias,
                           const float* __restrict__ qkv,  // attn out in q-region
                           const void* __restrict__ x, const int* __restrict__ flag,
                           void* __restrict__ out) {
    __shared__ __align__(16) float As[16][68];
    __shared__ __align__(16) float Bs[16][68];
    if (*flag)
        gemm_body<false, true, true, true, true>(W, bias, qkv, (size_t)1536 * PP, x,
                                                 nullptr, nullptr, nullptr, nullptr,
                                                 out, (size_t)CCH * PP, As, Bs);
    else
        gemm_body<false, true, false, true, false>(W, bias, qkv, (size_t)1536 * PP, x,
                                                   nullptr, nullptr, nullptr, nullptr,
                                                   out, (size_t)CCH * PP, As, Bs);
}

// ---------------------------------------------------------------------------
// Kernel 3: flash-style attention, f32 VALU.  Block = (b, h, 64-query tile);
// grid 2048.  Per K/V tile of 64: S = Q.K^T (64x64x64 outer-product GEMM),
// online softmax in registers (row = 16 lanes of one wave, shuffle reduce),
// P written into the K LDS buffer (reuse keeps LDS at 52 KB -> 3 blocks/CU),
// then O += P.V (second outer-product GEMM, float4 LDS reads).
// qkv layout (B, 3C, P), row = h*64+d; q=[0,512) k=[512,1024) v=[1024,1536).
// Output overwrites the q-region in place (disjoint tiles across blocks).
// ---------------------------------------------------------------------------
__launch_bounds__(256)
__global__ void fattn_k(float* __restrict__ qkv) {
    __shared__ __align__(16) float Qs[64][68];   // [d][q]
    __shared__ __align__(16) float Ks[64][68];   // [d][j]; reused as P[q][j], then O^T[d][q]
    __shared__ __align__(16) float Vs[64][68];   // [j][d] (transposed on store)
    const int tid = threadIdx.x;
    const int q0 = blockIdx.x * 64;
    const int h  = blockIdx.y;
    const int b  = blockIdx.z;
    const size_t baseq = ((size_t)(b * 1536 + h * 64)) * PP;
    const size_t basek = baseq + (size_t)512 * PP;
    const size_t basev = baseq + (size_t)1024 * PP;
    const int tx = tid & 15, ty = tid >> 4;     // q = ty*4+r, j/d = tx*4+c
    const int fi = tid & 15, fr = tid >> 4;     // staging: row fr(+16f), float4 fi

    // stage Q tile: Qs[d][q]
    #pragma unroll
    for (int f = 0; f < 4; f++) {
        int d = fr + f * 16;
        *(float4*)&Qs[d][fi * 4] =
            *(const float4*)(qkv + baseq + (size_t)d * PP + q0 + fi * 4);
    }
    float O[4][4] = {};
    float mrow[4] = {-3.0e38f, -3.0e38f, -3.0e38f, -3.0e38f};
    float lrow[4] = {};
    __syncthreads();

    for (int j0 = 0; j0 < PP; j0 += 64) {
        // stage K [d][j] and V transposed [j][d]
        #pragma unroll
        for (int f = 0; f < 4; f++) {
            int d = fr + f * 16;
            *(float4*)&Ks[d][fi * 4] =
                *(const float4*)(qkv + basek + (size_t)d * PP + j0 + fi * 4);
            float4 vv = *(const float4*)(qkv + basev + (size_t)d * PP + j0 + fi * 4);
            Vs[fi * 4 + 0][d] = vv.x; Vs[fi * 4 + 1][d] = vv.y;
            Vs[fi * 4 + 2][d] = vv.z; Vs[fi * 4 + 3][d] = vv.w;
        }
        __syncthreads();

        // GEMM1: s[q][j] = sum_d Qs[d][q] * Ks[d][j]
        float s[4][4] = {};
        #pragma unroll 8
        for (int d = 0; d < 64; d++) {
            float4 a  = *(const float4*)&Qs[d][ty * 4];
            float4 bb = *(const float4*)&Ks[d][tx * 4];
            s[0][0] += a.x * bb.x; s[0][1] += a.x * bb.y;
            s[0][2] += a.x * bb.z; s[0][3] += a.x * bb.w;
            s[1][0] += a.y * bb.x; s[1][1] += a.y * bb.y;
            s[1][2] += a.y * bb.z; s[1][3] += a.y * bb.w;
            s[2][0] += a.z * bb.x; s[2][1] += a.z * bb.y;
            s[2][2] += a.z * bb.z; s[2][3] += a.z * bb.w;
            s[3][0] += a.w * bb.x; s[3][1] += a.w * bb.y;
            s[3][2] += a.w * bb.z; s[3][3] += a.w * bb.w;
        }
        __syncthreads();   // all lanes done reading Ks -> safe to overwrite with P

        // online softmax per q-row (row = 16 tx lanes within one wave)
        #pragma unroll
        for (int r = 0; r < 4; r++) {
            float s0 = s[r][0] * 0.125f, s1 = s[r][1] * 0.125f;
            float s2 = s[r][2] * 0.125f, s3 = s[r][3] * 0.125f;
            float tm = fmaxf(fmaxf(s0, s1), fmaxf(s2, s3));
            tm = fmaxf(tm, __shfl_xor(tm, 1));
            tm = fmaxf(tm, __shfl_xor(tm, 2));
            tm = fmaxf(tm, __shfl_xor(tm, 4));
            tm = fmaxf(tm, __shfl_xor(tm, 8));
            float mnew  = fmaxf(mrow[r], tm);
            float alpha = __expf(mrow[r] - mnew);
            mrow[r] = mnew;
            float p0 = __expf(s0 - mnew), p1 = __expf(s1 - mnew);
            float p2 = __expf(s2 - mnew), p3 = __expf(s3 - mnew);
            float ts = p0 + p1 + p2 + p3;
            ts += __shfl_xor(ts, 1);
            ts += __shfl_xor(ts, 2);
            ts += __shfl_xor(ts, 4);
            ts += __shfl_xor(ts, 8);
            lrow[r] = lrow[r] * alpha + ts;
            O[r][0] *= alpha; O[r][1] *= alpha; O[r][2] *= alpha; O[r][3] *= alpha;
            *(float4*)&Ks[ty * 4 + r][tx * 4] = make_float4(p0, p1, p2, p3);
        }
        __syncthreads();

        // GEMM2: O[q][d] += sum_j P[q][j] * Vs[j][d]
        #pragma unroll 4
        for (int j4 = 0; j4 < 64; j4 += 4) {
            float4 pr0 = *(const float4*)&Ks[ty * 4 + 0][j4];
            float4 pr1 = *(const float4*)&Ks[ty * 4 + 1][j4];
            float4 pr2 = *(const float4*)&Ks[ty * 4 + 2][j4];
            float4 pr3 = *(const float4*)&Ks[ty * 4 + 3][j4];
            float4 v0 = *(const float4*)&Vs[j4 + 0][tx * 4];
            float4 v1 = *(const float4*)&Vs[j4 + 1][tx * 4];
            float4 v2 = *(const float4*)&Vs[j4 + 2][tx * 4];
            float4 v3 = *(const float4*)&Vs[j4 + 3][tx * 4];
            O[0][0] += pr0.x*v0.x + pr0.y*v1.x + pr0.z*v2.x + pr0.w*v3.x;
            O[0][1] += pr0.x*v0.y + pr0.y*v1.y + pr0.z*v2.y + pr0.w*v3.y;
            O[0][2] += pr0.x*v0.z + pr0.y*v1.z + pr0.z*v2.z + pr0.w*v3.z;
            O[0][3] += pr0.x*v0.w + pr0.y*v1.w + pr0.z*v2.w + pr0.w*v3.w;
            O[1][0] += pr1.x*v0.x + pr1.y*v1.x + pr1.z*v2.x + pr1.w*v3.x;
            O[1][1] += pr1.x*v0.y + pr1.y*v1.y + pr1.z*v2.y + pr1.w*v3.y;
            O[1][2] += pr1.x*v0.z + pr1.y*v1.z + pr1.z*v2.z + pr1.w*v3.z;
            O[1][3] += pr1.x*v0.w + pr1.y*v1.w + pr1.z*v2.w + pr1.w*v3.w;
            O[2][0] += pr2.x*v0.x + pr2.y*v1.x + pr2.z*v2.x + pr2.w*v3.x;
            O[2][1] += pr2.x*v0.y + pr2.y*v1.y + pr2.z*v2.y + pr2.w*v3.y;
            O[2][2] += pr2.x*v0.z + pr2.y*v1.z + pr2.z*v2.z + pr2.w*v3.z;
            O[2][3] += pr2.x*v0.w + pr2.y*v1.w + pr2.z*v2.w + pr2.w*v3.w;
            O[3][0] += pr3.x*v0.x + pr3.y*v1.x + pr3.z*v2.x + pr3.w*v3.x;
            O[3][1] += pr3.x*v0.y + pr3.y*v1.y + pr3.z*v2.y + pr3.w*v3.y;
            O[3][2] += pr3.x*v0.z + pr3.y*v1.z + pr3.z*v2.z + pr3.w*v3.z;
            O[3][3] += pr3.x*v0.w + pr3.y*v1.w + pr3.z*v2.w + pr3.w*v3.w;
        }
        __syncthreads();   // done with Ks(P)/Vs before next stage
    }

    // epilogue: normalize, transpose O into Ks as [d][q], coalesced store
    {
        float r0 = 1.f / lrow[0], r1 = 1.f / lrow[1];
        float r2 = 1.f / lrow[2], r3 = 1.f / lrow[3];
        #pragma unroll
        for (int c = 0; c < 4; c++) {
            *(float4*)&Ks[tx * 4 + c][ty * 4] =
                make_float4(O[0][c] * r0, O[1][c] * r1, O[2][c] * r2, O[3][c] * r3);
        }
    }
    __syncthreads();
    #pragma unroll
    for (int f = 0; f < 4; f++) {
        int d = fr + f * 16;
        *(float4*)(qkv + baseq + (size_t)d * PP + q0 + fi * 4) =
            *(const float4*)&Ks[d][fi * 4];
    }
}

// ---------------------------------------------------------------------------
extern "C" void kernel_launch(void* const* d_in, const int* in_sizes, int n_in,
                              void* d_out, int out_size, void* d_ws, size_t ws_size,
                              hipStream_t stream) {
    const void* x     = d_in[0];
    const void* gamma = d_in[1];
    const void* beta  = d_in[2];
    const void* w_qkv = d_in[3];
    const void* b_qkv = d_in[4];
    const void* w_out = d_in[5];
    const void* b_out = d_in[6];

    char* ws = (char*)d_ws;
    int*   flag = (int*)ws;                    // 4 B
    float* mean = (float*)(ws + 512);          // 128 floats
    float* rstd = (float*)(ws + 1536);         // 128 floats
    float* qkv  = (float*)(ws + 4096);         // 16*1536*1024 f32 = 96 MB

    detect_k<<<1, 256, 0, stream>>>((const u32*)x, flag);
    gn_stats_k<<<128, 256, 0, stream>>>(x, flag, mean, rstd);
    gemm_qkv_k<<<dim3(PP / 64, 1536 / 64, BB), 256, 0, stream>>>(
        w_qkv, b_qkv, x, flag, mean, rstd, gamma, beta, qkv);
    fattn_k<<<dim3(PP / 64, NHD, BB), 256, 0, stream>>>(qkv);
    gemm_out_k<<<dim3(PP / 64, 512 / 64, BB), 256, 0, stream>>>(
        w_out, b_out, qkv, x, flag, d_out);
}

// Round 6
// 683.234 us; speedup vs baseline: 5.0895x; 1.7094x over previous
//
#include <hip/hip_runtime.h>
#include <hip/hip_bf16.h>

// B=16, C=512, H=W=32 -> P=1024 pixels, 8 groups (64 ch), 8 heads (hd=64).
// Inputs f32 (verified R3/R4), output f32.  Internals bf16 + fp32 accum.
#define BB   16
#define CCH  512
#define PP   1024
#define NHD  8

typedef unsigned short u16;
typedef unsigned int   u32;
typedef __attribute__((ext_vector_type(8))) short bf16x8;   // 8 bf16 = 4 VGPR
typedef __attribute__((ext_vector_type(4))) float f32x4;

__device__ __forceinline__ float us2f(u16 u) {
    return __uint_as_float(((u32)u) << 16);
}
__device__ __forceinline__ u16 f2bu(float f) {
    __hip_bfloat16 h = __float2bfloat16(f);   // RNE
    return *reinterpret_cast<u16*>(&h);
}

// ---------------------------------------------------------------------------
// Kernel 1: per-(batch,group) mean / rstd.  128 blocks x 256 threads.
// ---------------------------------------------------------------------------
__launch_bounds__(256)
__global__ void gn_stats_k(const float* __restrict__ x,
                           float* __restrict__ mean, float* __restrict__ rstd) {
    int bg = blockIdx.x;
    const float4* xp = (const float4*)(x + (size_t)bg * 65536);
    float s = 0.f, ss = 0.f;
    for (int i = threadIdx.x; i < 16384; i += 256) {
        float4 v = xp[i];
        s  += v.x + v.y + v.z + v.w;
        ss += v.x*v.x + v.y*v.y + v.z*v.z + v.w*v.w;
    }
    __shared__ float sh[256], sq[256];
    sh[threadIdx.x] = s; sq[threadIdx.x] = ss;
    __syncthreads();
    for (int off = 128; off > 0; off >>= 1) {
        if (threadIdx.x < off) {
            sh[threadIdx.x] += sh[threadIdx.x + off];
            sq[threadIdx.x] += sq[threadIdx.x + off];
        }
        __syncthreads();
    }
    if (threadIdx.x == 0) {
        float m   = sh[0] * (1.f / 65536.f);
        float var = sq[0] * (1.f / 65536.f) - m * m;
        mean[bg] = m;
        rstd[bg] = rsqrtf(var + 1e-5f);
    }
}

// ---------------------------------------------------------------------------
// Kernel 2: GN-normalize + convert + transpose: x[b][c][p] f32 ->
// xb_t[b][p][c] bf16 (p-major so MFMA B-frags read k-contiguous).
// ---------------------------------------------------------------------------
__launch_bounds__(256)
__global__ void conv_x_k(const float* __restrict__ x,
                         const float* __restrict__ mean, const float* __restrict__ rstd,
                         const float* __restrict__ gamma, const float* __restrict__ beta,
                         u16* __restrict__ xbt) {
    __shared__ u16 T[64][73];
    const int tid = threadIdx.x;
    const int p0 = blockIdx.x * 64;
    const int c0 = blockIdx.y * 64;
    const int b  = blockIdx.z;
    {
        int ci = tid >> 2, ps = (tid & 3) * 16;
        int c = c0 + ci;
        int bg = (b << 3) + (c >> 6);
        float sc = rstd[bg] * gamma[c];
        float sf = beta[c] - mean[bg] * sc;
        const float* xp = x + ((size_t)(b * CCH + c)) * PP + p0 + ps;
        #pragma unroll
        for (int j4 = 0; j4 < 4; j4++) {
            float4 v = *(const float4*)(xp + j4 * 4);
            T[ps + j4*4 + 0][ci] = f2bu(v.x * sc + sf);
            T[ps + j4*4 + 1][ci] = f2bu(v.y * sc + sf);
            T[ps + j4*4 + 2][ci] = f2bu(v.z * sc + sf);
            T[ps + j4*4 + 3][ci] = f2bu(v.w * sc + sf);
        }
    }
    __syncthreads();
    {
        int pi = tid >> 2, cs = (tid & 3) * 16;
        u16* dst = xbt + ((size_t)(b * PP) + p0 + pi) * CCH + c0 + cs;
        #pragma unroll
        for (int j4 = 0; j4 < 4; j4++) {
            ushort4 o;
            o.x = T[pi][cs + j4*4 + 0]; o.y = T[pi][cs + j4*4 + 1];
            o.z = T[pi][cs + j4*4 + 2]; o.w = T[pi][cs + j4*4 + 3];
            *(ushort4*)(dst + j4 * 4) = o;
        }
    }
}

// ---------------------------------------------------------------------------
// Kernel 3: weights f32 -> bf16.
// ---------------------------------------------------------------------------
__launch_bounds__(256)
__global__ void conv_w_k(const float* __restrict__ w1, const float* __restrict__ w2,
                         u16* __restrict__ d1, u16* __restrict__ d2) {
    int id = blockIdx.x * 256 + threadIdx.x;
    const float* s; u16* d; int off;
    if (id < 196608) { s = w1; d = d1; off = id * 4; }
    else             { s = w2; d = d2; off = (id - 196608) * 4; }
    float4 v = *(const float4*)(s + off);
    ushort4 o;
    o.x = f2bu(v.x); o.y = f2bu(v.y); o.z = f2bu(v.z); o.w = f2bu(v.w);
    *(ushort4*)(d + off) = o;
}

// ---------------------------------------------------------------------------
// Kernel 4/6: MFMA GEMM.  out[b][m][p] = sum_k W[m][k] * actT[b][p][k].
// 128x128 tile, BK=32, 4 waves, 4x4 frags of mfma_f32_16x16x32_bf16.
// Layouts (m89/m91/m120):  A[m=lane&15][k=quad*8+j], B[k=quad*8+j][n=lane&15],
// D: row=quad*4+reg, col=lane&15.  LDS [128][40] u16.
// R5 bug fixed: staging now loads TWO uint4 per thread per matrix
// (2 thr/row x 16 u16 = full 32-k coverage; R5 covered only half).
// ---------------------------------------------------------------------------
template<bool F32OUT>
__launch_bounds__(256)
__global__ void mgemm_k(const u16* __restrict__ Wb, const float* __restrict__ bias,
                        const u16* __restrict__ actT, const float* __restrict__ resid,
                        void* __restrict__ out) {
    __shared__ __align__(16) u16 smem[17408];    // staging 2x5120 | Cb 128x136
    u16* As = smem;                              // [128][40]
    u16* Bs = smem + 5120;                       // [128][40]
    const int tid = threadIdx.x;
    const int p0 = blockIdx.x * 128;
    const int m0 = blockIdx.y * 128;
    const int b  = blockIdx.z;
    const int w = tid >> 6, l = tid & 63, quad = l >> 4, lm = l & 15;
    const int mo = (w >> 1) * 64, no = (w & 1) * 64;

    f32x4 acc[4][4] = {};

    const int srow = tid >> 1, sks = (tid & 1) << 4;   // 2 thr/row, 16 u16 each
    const u16* wp = Wb + (size_t)(m0 + srow) * CCH + sks;
    const u16* ap = actT + (size_t)b * PP * CCH + (size_t)(p0 + srow) * CCH + sks;
    u16* asw = &As[srow * 40 + sks];
    u16* bsw = &Bs[srow * 40 + sks];

    for (int k0 = 0; k0 < CCH; k0 += 32) {
        uint4 aw0 = *(const uint4*)(wp + k0);
        uint4 aw1 = *(const uint4*)(wp + k0 + 8);
        uint4 bw0 = *(const uint4*)(ap + k0);
        uint4 bw1 = *(const uint4*)(ap + k0 + 8);
        *(uint4*)asw = aw0;  *(uint4*)(asw + 8) = aw1;
        *(uint4*)bsw = bw0;  *(uint4*)(bsw + 8) = bw1;
        __syncthreads();
        bf16x8 af[4], bfr[4];
        #pragma unroll
        for (int mi = 0; mi < 4; mi++)
            af[mi] = *(const bf16x8*)&As[(mo + mi*16 + lm) * 40 + quad * 8];
        #pragma unroll
        for (int ni = 0; ni < 4; ni++)
            bfr[ni] = *(const bf16x8*)&Bs[(no + ni*16 + lm) * 40 + quad * 8];
        #pragma unroll
        for (int mi = 0; mi < 4; mi++)
            #pragma unroll
            for (int ni = 0; ni < 4; ni++)
                acc[mi][ni] = __builtin_amdgcn_mfma_f32_16x16x32_bf16(
                    af[mi], bfr[ni], acc[mi][ni], 0, 0, 0);
        __syncthreads();
    }

    if (!F32OUT) {
        // bf16 epilogue: bias, bounce through LDS Cb[m][p] for coalesced stores
        u16* Cb = smem;                          // [128][136]
        #pragma unroll
        for (int mi = 0; mi < 4; mi++) {
            f32x4 bv = *(const f32x4*)&bias[m0 + mo + mi*16 + quad*4];
            #pragma unroll
            for (int ni = 0; ni < 4; ni++) {
                int colp = no + ni*16 + lm;
                int rowb = mo + mi*16 + quad*4;
                #pragma unroll
                for (int r = 0; r < 4; r++)
                    Cb[(rowb + r) * 136 + colp] = f2bu(acc[mi][ni][r] + bv[r]);
            }
        }
        __syncthreads();
        int row = tid >> 1, half = tid & 1;
        u16* og = (u16*)out + (size_t)b * 1536 * PP + (size_t)(m0 + row) * PP
                + p0 + half * 64;
        const u16* src = &Cb[row * 136 + half * 64];
        #pragma unroll
        for (int i = 0; i < 8; i++)
            *(uint4*)(og + i * 8) = *(const uint4*)(src + i * 8);
    } else {
        // f32 epilogue: bias + residual, direct stores
        float* of = (float*)out;
        #pragma unroll
        for (int mi = 0; mi < 4; mi++) {
            f32x4 bv = *(const f32x4*)&bias[m0 + mo + mi*16 + quad*4];
            #pragma unroll
            for (int ni = 0; ni < 4; ni++) {
                int p = p0 + no + ni*16 + lm;
                #pragma unroll
                for (int r = 0; r < 4; r++) {
                    int m = m0 + mo + mi*16 + quad*4 + r;
                    size_t idx = ((size_t)b * CCH + m) * PP + p;
                    of[idx] = acc[mi][ni][r] + bv[r] + resid[idx];
                }
            }
        }
    }
}

// ---------------------------------------------------------------------------
// Kernel 5: flash attention, f32 VALU on bf16 global IO (unchanged R4 logic).
// qkv bf16 [b][1536][p]: q=[0,512) k=[512,1024) v=[1024,1536), row=h*64+d.
// Output ao bf16 [b][p][512] (p-major, feeds out-proj MFMA GEMM directly).
// ---------------------------------------------------------------------------
__launch_bounds__(256)
__global__ void fattn_k(const u16* __restrict__ qkv, u16* __restrict__ ao) {
    __shared__ __align__(16) float Qs[64][68];   // [d][q]
    __shared__ __align__(16) float Ks[64][68];   // [d][j]; reused as P[q][j]
    __shared__ __align__(16) float Vs[64][68];   // [j][d]
    const int tid = threadIdx.x;
    const int q0 = blockIdx.x * 64;
    const int h  = blockIdx.y;
    const int b  = blockIdx.z;
    const size_t baseq = ((size_t)(b * 1536 + h * 64)) * PP;
    const size_t basek = baseq + (size_t)512 * PP;
    const size_t basev = baseq + (size_t)1024 * PP;
    const int tx = tid & 15, ty = tid >> 4;
    const int fi = tid & 15, fr = tid >> 4;

    #pragma unroll
    for (int f = 0; f < 4; f++) {
        int d = fr + f * 16;
        ushort4 u = *(const ushort4*)(qkv + baseq + (size_t)d * PP + q0 + fi * 4);
        Qs[d][fi*4 + 0] = us2f(u.x); Qs[d][fi*4 + 1] = us2f(u.y);
        Qs[d][fi*4 + 2] = us2f(u.z); Qs[d][fi*4 + 3] = us2f(u.w);
    }
    float O[4][4] = {};
    float mrow[4] = {-3.0e38f, -3.0e38f, -3.0e38f, -3.0e38f};
    float lrow[4] = {};
    __syncthreads();

    for (int j0 = 0; j0 < PP; j0 += 64) {
        #pragma unroll
        for (int f = 0; f < 4; f++) {
            int d = fr + f * 16;
            ushort4 ku = *(const ushort4*)(qkv + basek + (size_t)d * PP + j0 + fi * 4);
            Ks[d][fi*4 + 0] = us2f(ku.x); Ks[d][fi*4 + 1] = us2f(ku.y);
            Ks[d][fi*4 + 2] = us2f(ku.z); Ks[d][fi*4 + 3] = us2f(ku.w);
            ushort4 vu = *(const ushort4*)(qkv + basev + (size_t)d * PP + j0 + fi * 4);
            Vs[fi*4 + 0][d] = us2f(vu.x); Vs[fi*4 + 1][d] = us2f(vu.y);
            Vs[fi*4 + 2][d] = us2f(vu.z); Vs[fi*4 + 3][d] = us2f(vu.w);
        }
        __syncthreads();

        float s[4][4] = {};
        #pragma unroll 8
        for (int d = 0; d < 64; d++) {
            float4 a  = *(const float4*)&Qs[d][ty * 4];
            float4 bb = *(const float4*)&Ks[d][tx * 4];
            s[0][0] += a.x * bb.x; s[0][1] += a.x * bb.y;
            s[0][2] += a.x * bb.z; s[0][3] += a.x * bb.w;
            s[1][0] += a.y * bb.x; s[1][1] += a.y * bb.y;
            s[1][2] += a.y * bb.z; s[1][3] += a.y * bb.w;
            s[2][0] += a.z * bb.x; s[2][1] += a.z * bb.y;
            s[2][2] += a.z * bb.z; s[2][3] += a.z * bb.w;
            s[3][0] += a.w * bb.x; s[3][1] += a.w * bb.y;
            s[3][2] += a.w * bb.z; s[3][3] += a.w * bb.w;
        }
        __syncthreads();

        #pragma unroll
        for (int r = 0; r < 4; r++) {
            float s0 = s[r][0] * 0.125f, s1 = s[r][1] * 0.125f;
            float s2 = s[r][2] * 0.125f, s3 = s[r][3] * 0.125f;
            float tm = fmaxf(fmaxf(s0, s1), fmaxf(s2, s3));
            tm = fmaxf(tm, __shfl_xor(tm, 1));
            tm = fmaxf(tm, __shfl_xor(tm, 2));
            tm = fmaxf(tm, __shfl_xor(tm, 4));
            tm = fmaxf(tm, __shfl_xor(tm, 8));
            float mnew  = fmaxf(mrow[r], tm);
            float alpha = __expf(mrow[r] - mnew);
            mrow[r] = mnew;
            float p0 = __expf(s0 - mnew), p1 = __expf(s1 - mnew);
            float p2 = __expf(s2 - mnew), p3 = __expf(s3 - mnew);
            float ts = p0 + p1 + p2 + p3;
            ts += __shfl_xor(ts, 1);
            ts += __shfl_xor(ts, 2);
            ts += __shfl_xor(ts, 4);
            ts += __shfl_xor(ts, 8);
            lrow[r] = lrow[r] * alpha + ts;
            O[r][0] *= alpha; O[r][1] *= alpha; O[r][2] *= alpha; O[r][3] *= alpha;
            *(float4*)&Ks[ty * 4 + r][tx * 4] = make_float4(p0, p1, p2, p3);
        }
        __syncthreads();

        #pragma unroll 4
        for (int j4 = 0; j4 < 64; j4 += 4) {
            float4 pr0 = *(const float4*)&Ks[ty * 4 + 0][j4];
            float4 pr1 = *(const float4*)&Ks[ty * 4 + 1][j4];
            float4 pr2 = *(const float4*)&Ks[ty * 4 + 2][j4];
            float4 pr3 = *(const float4*)&Ks[ty * 4 + 3][j4];
            float4 v0 = *(const float4*)&Vs[j4 + 0][tx * 4];
            float4 v1 = *(const float4*)&Vs[j4 + 1][tx * 4];
            float4 v2 = *(const float4*)&Vs[j4 + 2][tx * 4];
            float4 v3 = *(const float4*)&Vs[j4 + 3][tx * 4];
            O[0][0] += pr0.x*v0.x + pr0.y*v1.x + pr0.z*v2.x + pr0.w*v3.x;
            O[0][1] += pr0.x*v0.y + pr0.y*v1.y + pr0.z*v2.y + pr0.w*v3.y;
            O[0][2] += pr0.x*v0.z + pr0.y*v1.z + pr0.z*v2.z + pr0.w*v3.z;
            O[0][3] += pr0.x*v0.w + pr0.y*v1.w + pr0.z*v2.w + pr0.w*v3.w;
            O[1][0] += pr1.x*v0.x + pr1.y*v1.x + pr1.z*v2.x + pr1.w*v3.x;
            O[1][1] += pr1.x*v0.y + pr1.y*v1.y + pr1.z*v2.y + pr1.w*v3.y;
            O[1][2] += pr1.x*v0.z + pr1.y*v1.z + pr1.z*v2.z + pr1.w*v3.z;
            O[1][3] += pr1.x*v0.w + pr1.y*v1.w + pr1.z*v2.w + pr1.w*v3.w;
            O[2][0] += pr2.x*v0.x + pr2.y*v1.x + pr2.z*v2.x + pr2.w*v3.x;
            O[2][1] += pr2.x*v0.y + pr2.y*v1.y + pr2.z*v2.y + pr2.w*v3.y;
            O[2][2] += pr2.x*v0.z + pr2.y*v1.z + pr2.z*v2.z + pr2.w*v3.z;
            O[2][3] += pr2.x*v0.w + pr2.y*v1.w + pr2.z*v2.w + pr2.w*v3.w;
            O[3][0] += pr3.x*v0.x + pr3.y*v1.x + pr3.z*v2.x + pr3.w*v3.x;
            O[3][1] += pr3.x*v0.y + pr3.y*v1.y + pr3.z*v2.y + pr3.w*v3.y;
            O[3][2] += pr3.x*v0.z + pr3.y*v1.z + pr3.z*v2.z + pr3.w*v3.z;
            O[3][3] += pr3.x*v0.w + pr3.y*v1.w + pr3.z*v2.w + pr3.w*v3.w;
        }
        __syncthreads();
    }

    // epilogue: normalize, write ao[b][p][c] bf16 (d-contiguous -> coalesced)
    {
        size_t aob = ((size_t)(b * PP) + q0) * CCH + (size_t)h * 64 + tx * 4;
        #pragma unroll
        for (int r = 0; r < 4; r++) {
            float rr = 1.f / lrow[r];
            ushort4 o;
            o.x = f2bu(O[r][0] * rr); o.y = f2bu(O[r][1] * rr);
            o.z = f2bu(O[r][2] * rr); o.w = f2bu(O[r][3] * rr);
            *(ushort4*)(ao + aob + (size_t)(ty * 4 + r) * CCH) = o;
        }
    }
}

// ---------------------------------------------------------------------------
extern "C" void kernel_launch(void* const* d_in, const int* in_sizes, int n_in,
                              void* d_out, int out_size, void* d_ws, size_t ws_size,
                              hipStream_t stream) {
    const float* x     = (const float*)d_in[0];
    const float* gamma = (const float*)d_in[1];
    const float* beta  = (const float*)d_in[2];
    const float* w_qkv = (const float*)d_in[3];
    const float* b_qkv = (const float*)d_in[4];
    const float* w_out = (const float*)d_in[5];
    const float* b_out = (const float*)d_in[6];

    char* ws = (char*)d_ws;
    float* mean = (float*)ws;                   // 128 f32
    float* rstd = (float*)(ws + 1024);          // 128 f32
    u16* wqb = (u16*)(ws + 4096);               // 1536*512
    u16* wob = wqb + 1536 * 512;                // 512*512
    u16* xbt = wob + 512 * 512;                 // [b][p][c]  8.4M elems
    u16* ao  = xbt + (size_t)BB * PP * CCH;     // [b][p][c]  8.4M elems
    u16* qkv = ao  + (size_t)BB * PP * CCH;     // [b][1536][p] 25.2M elems (~86 MB)

    gn_stats_k<<<128, 256, 0, stream>>>(x, mean, rstd);
    conv_x_k<<<dim3(16, 8, 16), 256, 0, stream>>>(x, mean, rstd, gamma, beta, xbt);
    conv_w_k<<<1024, 256, 0, stream>>>(w_qkv, w_out, wqb, wob);
    mgemm_k<false><<<dim3(8, 12, 16), 256, 0, stream>>>(wqb, b_qkv, xbt, nullptr, qkv);
    fattn_k<<<dim3(16, 8, 16), 256, 0, stream>>>(qkv, ao);
    mgemm_k<true><<<dim3(8, 4, 16), 256, 0, stream>>>(wob, b_out, ao, x, d_out);
}

// Round 8
// 328.171 us; speedup vs baseline: 10.5960x; 2.0819x over previous
//
#include <hip/hip_runtime.h>
#include <hip/hip_bf16.h>

// B=16, C=512, H=W=32 -> P=1024 pixels, 8 groups (64 ch), 8 heads (hd=64).
// Inputs f32, output f32.  Internals bf16 + fp32 accum (validated R6).
#define BB   16
#define CCH  512
#define PP   1024
#define NHD  8

typedef unsigned short u16;
typedef unsigned int   u32;
typedef __attribute__((ext_vector_type(8))) short bf16x8;   // 8 bf16 = 4 VGPR
typedef __attribute__((ext_vector_type(4))) float f32x4;

__device__ __forceinline__ float us2f(u16 u) {
    return __uint_as_float(((u32)u) << 16);
}
__device__ __forceinline__ u16 f2bu(float f) {
    __hip_bfloat16 h = __float2bfloat16(f);   // RNE
    return *reinterpret_cast<u16*>(&h);
}

// ---------------------------------------------------------------------------
// Kernel 1: per-(batch,group) mean / rstd.
// ---------------------------------------------------------------------------
__launch_bounds__(256)
__global__ void gn_stats_k(const float* __restrict__ x,
                           float* __restrict__ mean, float* __restrict__ rstd) {
    int bg = blockIdx.x;
    const float4* xp = (const float4*)(x + (size_t)bg * 65536);
    float s = 0.f, ss = 0.f;
    for (int i = threadIdx.x; i < 16384; i += 256) {
        float4 v = xp[i];
        s  += v.x + v.y + v.z + v.w;
        ss += v.x*v.x + v.y*v.y + v.z*v.z + v.w*v.w;
    }
    __shared__ float sh[256], sq[256];
    sh[threadIdx.x] = s; sq[threadIdx.x] = ss;
    __syncthreads();
    for (int off = 128; off > 0; off >>= 1) {
        if (threadIdx.x < off) {
            sh[threadIdx.x] += sh[threadIdx.x + off];
            sq[threadIdx.x] += sq[threadIdx.x + off];
        }
        __syncthreads();
    }
    if (threadIdx.x == 0) {
        float m   = sh[0] * (1.f / 65536.f);
        float var = sq[0] * (1.f / 65536.f) - m * m;
        mean[bg] = m;
        rstd[bg] = rsqrtf(var + 1e-5f);
    }
}

// ---------------------------------------------------------------------------
// Kernel 2: GN-normalize + convert + transpose: x[b][c][p] f32 ->
// xbt[b][p][c] bf16.
// ---------------------------------------------------------------------------
__launch_bounds__(256)
__global__ void conv_x_k(const float* __restrict__ x,
                         const float* __restrict__ mean, const float* __restrict__ rstd,
                         const float* __restrict__ gamma, const float* __restrict__ beta,
                         u16* __restrict__ xbt) {
    __shared__ u16 T[64][73];
    const int tid = threadIdx.x;
    const int p0 = blockIdx.x * 64;
    const int c0 = blockIdx.y * 64;
    const int b  = blockIdx.z;
    {
        int ci = tid >> 2, ps = (tid & 3) * 16;
        int c = c0 + ci;
        int bg = (b << 3) + (c >> 6);
        float sc = rstd[bg] * gamma[c];
        float sf = beta[c] - mean[bg] * sc;
        const float* xp = x + ((size_t)(b * CCH + c)) * PP + p0 + ps;
        #pragma unroll
        for (int j4 = 0; j4 < 4; j4++) {
            float4 v = *(const float4*)(xp + j4 * 4);
            T[ps + j4*4 + 0][ci] = f2bu(v.x * sc + sf);
            T[ps + j4*4 + 1][ci] = f2bu(v.y * sc + sf);
            T[ps + j4*4 + 2][ci] = f2bu(v.z * sc + sf);
            T[ps + j4*4 + 3][ci] = f2bu(v.w * sc + sf);
        }
    }
    __syncthreads();
    {
        int pi = tid >> 2, cs = (tid & 3) * 16;
        u16* dst = xbt + ((size_t)(b * PP) + p0 + pi) * CCH + c0 + cs;
        #pragma unroll
        for (int j4 = 0; j4 < 4; j4++) {
            ushort4 o;
            o.x = T[pi][cs + j4*4 + 0]; o.y = T[pi][cs + j4*4 + 1];
            o.z = T[pi][cs + j4*4 + 2]; o.w = T[pi][cs + j4*4 + 3];
            *(ushort4*)(dst + j4 * 4) = o;
        }
    }
}

// ---------------------------------------------------------------------------
// Kernel 3: weights f32 -> bf16.
// ---------------------------------------------------------------------------
__launch_bounds__(256)
__global__ void conv_w_k(const float* __restrict__ w1, const float* __restrict__ w2,
                         u16* __restrict__ d1, u16* __restrict__ d2) {
    int id = blockIdx.x * 256 + threadIdx.x;
    const float* s; u16* d; int off;
    if (id < 196608) { s = w1; d = d1; off = id * 4; }
    else             { s = w2; d = d2; off = (id - 196608) * 4; }
    float4 v = *(const float4*)(s + off);
    ushort4 o;
    o.x = f2bu(v.x); o.y = f2bu(v.y); o.z = f2bu(v.z); o.w = f2bu(v.w);
    *(ushort4*)(d + off) = o;
}

// ---------------------------------------------------------------------------
// Kernel 4: qkv MFMA GEMM.  acc[b][m][p] = sum_k W[m][k]*xbt[b][p][k] + bias.
// 128x128 tile, BK=32, 4 waves, 4x4 frags of mfma_f32_16x16x32_bf16
// (layouts validated in-HW R6).  Epilogue by region:
//   m0<512   (Q): transposed store -> qT[b][p][m]        (bf16)
//   m0<1024  (K): transposed store -> kT[b][p][m-512]    (bf16)
//   else     (V): normal store     -> v[b][m-1024][p]    (bf16)
// ---------------------------------------------------------------------------
__launch_bounds__(256)
__global__ void mgemm_qkv_k(const u16* __restrict__ Wb, const float* __restrict__ bias,
                            const u16* __restrict__ actT,
                            u16* __restrict__ qT, u16* __restrict__ kT,
                            u16* __restrict__ v) {
    __shared__ __align__(16) u16 smem[17408];    // staging 2x5120 | Cb 128x136
    u16* As = smem;                              // [128][40]
    u16* Bs = smem + 5120;                       // [128][40]
    const int tid = threadIdx.x;
    const int p0 = blockIdx.x * 128;
    const int m0 = blockIdx.y * 128;
    const int b  = blockIdx.z;
    const int w = tid >> 6, l = tid & 63, quad = l >> 4, lm = l & 15;
    const int mo = (w >> 1) * 64, no = (w & 1) * 64;

    f32x4 acc[4][4] = {};

    const int srow = tid >> 1, sks = (tid & 1) << 4;
    const u16* wp = Wb + (size_t)(m0 + srow) * CCH + sks;
    const u16* ap = actT + (size_t)b * PP * CCH + (size_t)(p0 + srow) * CCH + sks;
    u16* asw = &As[srow * 40 + sks];
    u16* bsw = &Bs[srow * 40 + sks];

    for (int k0 = 0; k0 < CCH; k0 += 32) {
        uint4 aw0 = *(const uint4*)(wp + k0);
        uint4 aw1 = *(const uint4*)(wp + k0 + 8);
        uint4 bw0 = *(const uint4*)(ap + k0);
        uint4 bw1 = *(const uint4*)(ap + k0 + 8);
        *(uint4*)asw = aw0;  *(uint4*)(asw + 8) = aw1;
        *(uint4*)bsw = bw0;  *(uint4*)(bsw + 8) = bw1;
        __syncthreads();
        bf16x8 af[4], bfr[4];
        #pragma unroll
        for (int mi = 0; mi < 4; mi++)
            af[mi] = *(const bf16x8*)&As[(mo + mi*16 + lm) * 40 + quad * 8];
        #pragma unroll
        for (int ni = 0; ni < 4; ni++)
            bfr[ni] = *(const bf16x8*)&Bs[(no + ni*16 + lm) * 40 + quad * 8];
        #pragma unroll
        for (int mi = 0; mi < 4; mi++)
            #pragma unroll
            for (int ni = 0; ni < 4; ni++)
                acc[mi][ni] = __builtin_amdgcn_mfma_f32_16x16x32_bf16(
                    af[mi], bfr[ni], acc[mi][ni], 0, 0, 0);
        __syncthreads();
    }

    const int region = m0 >> 9;   // 0=Q 1=K 2=V
    if (region < 2) {
        // transposed bounce: Cb[p(128)][m stride 136]
        u16* Cb = smem;
        #pragma unroll
        for (int mi = 0; mi < 4; mi++) {
            f32x4 bv = *(const f32x4*)&bias[m0 + mo + mi*16 + quad*4];
            #pragma unroll
            for (int ni = 0; ni < 4; ni++) {
                int colp = no + ni*16 + lm;
                int rowb = mo + mi*16 + quad*4;
                #pragma unroll
                for (int r = 0; r < 4; r++)
                    Cb[colp * 136 + rowb + r] = f2bu(acc[mi][ni][r] + bv[r]);
            }
        }
        __syncthreads();
        int prow = tid >> 1, half = tid & 1;
        u16* base = (region == 0) ? qT : kT;
        u16* dst = base + ((size_t)b * PP + p0 + prow) * 512 + (m0 & 511) + half * 64;
        const u16* src = &Cb[prow * 136 + half * 64];
        #pragma unroll
        for (int i = 0; i < 8; i++)
            *(uint4*)(dst + i * 8) = *(const uint4*)(src + i * 8);
    } else {
        // normal bounce: Cb[m(128)][p stride 136] -> v[b][m-1024][p]
        u16* Cb = smem;
        #pragma unroll
        for (int mi = 0; mi < 4; mi++) {
            f32x4 bv = *(const f32x4*)&bias[m0 + mo + mi*16 + quad*4];
            #pragma unroll
            for (int ni = 0; ni < 4; ni++) {
                int colp = no + ni*16 + lm;
                int rowb = mo + mi*16 + quad*4;
                #pragma unroll
                for (int r = 0; r < 4; r++)
                    Cb[(rowb + r) * 136 + colp] = f2bu(acc[mi][ni][r] + bv[r]);
            }
        }
        __syncthreads();
        int row = tid >> 1, half = tid & 1;
        u16* dst = v + ((size_t)b * 512 + (m0 - 1024) + row) * PP + p0 + half * 64;
        const u16* src = &Cb[row * 136 + half * 64];
        #pragma unroll
        for (int i = 0; i < 8; i++)
            *(uint4*)(dst + i * 8) = *(const uint4*)(src + i * 8);
    }
}

// ---------------------------------------------------------------------------
// Kernel 5: MFMA flash attention.  Block = (b, h, 64-q tile), 4 waves, each
// wave owns 16 q rows.  Stagings are all direct copies:
//   Q from qT[b][q][c]  -> Ps LDS [q][d]   (A-operand of S; frags preloaded)
//   K from kT[b][j][c]  -> Ks LDS [j][d]   (B-operand of S)
//   V from v [b][c][p]  -> Vs LDS [d][j]   (B-operand of PV)
// Per j-tile: S = Q.K^T via 8 MFMAs; online softmax in regs (row = 16 lanes
// of a quad); P -> Ps LDS (bf16, C-layout -> A-layout transform); O += P.V
// via 8 MFMAs.  Output ao[b][p][512] bf16 via LDS bounce.
// ---------------------------------------------------------------------------
__launch_bounds__(256)
__global__ void fattn_k(const u16* __restrict__ qT, const u16* __restrict__ kT,
                        const u16* __restrict__ v, u16* __restrict__ ao) {
    __shared__ __align__(16) u16 Ps[64 * 72];   // Q staging, then P, then O out
    __shared__ __align__(16) u16 Ks[64 * 72];
    __shared__ __align__(16) u16 Vs[64 * 72];
    const int tid = threadIdx.x;
    const int q0 = blockIdx.x * 64;
    const int h  = blockIdx.y;
    const int b  = blockIdx.z;
    const int w = tid >> 6, l = tid & 63, quad = l >> 4, lm = l & 15;
    const int sr = tid >> 2, sc = (tid & 3) * 16;   // staging: 4 thr/row, 16 u16

    // stage Q -> Ps[q][d]
    {
        const u16* src = qT + ((size_t)b * PP + q0 + sr) * 512 + h * 64 + sc;
        *(uint4*)&Ps[sr * 72 + sc]     = *(const uint4*)src;
        *(uint4*)&Ps[sr * 72 + sc + 8] = *(const uint4*)(src + 8);
    }
    __syncthreads();
    bf16x8 qf0 = *(const bf16x8*)&Ps[(w * 16 + lm) * 72 + quad * 8];
    bf16x8 qf1 = *(const bf16x8*)&Ps[(w * 16 + lm) * 72 + 32 + quad * 8];

    f32x4 O[4] = {};
    float mrow[4] = {-3.0e38f, -3.0e38f, -3.0e38f, -3.0e38f};
    float lrow[4] = {};

    for (int j0 = 0; j0 < PP; j0 += 64) {
        // stage K [j][d] and V [d][j] (both direct copies)
        {
            const u16* ks = kT + ((size_t)b * PP + j0 + sr) * 512 + h * 64 + sc;
            *(uint4*)&Ks[sr * 72 + sc]     = *(const uint4*)ks;
            *(uint4*)&Ks[sr * 72 + sc + 8] = *(const uint4*)(ks + 8);
            const u16* vsrc = v + ((size_t)b * 512 + h * 64 + sr) * PP + j0 + sc;
            *(uint4*)&Vs[sr * 72 + sc]     = *(const uint4*)vsrc;
            *(uint4*)&Vs[sr * 72 + sc + 8] = *(const uint4*)(vsrc + 8);
        }
        __syncthreads();

        // S = Q.K^T  (rows w*16.., all 64 j)
        f32x4 s[4] = {};
        #pragma unroll
        for (int ni = 0; ni < 4; ni++) {
            bf16x8 kf0 = *(const bf16x8*)&Ks[(ni*16 + lm) * 72 + quad * 8];
            bf16x8 kf1 = *(const bf16x8*)&Ks[(ni*16 + lm) * 72 + 32 + quad * 8];
            s[ni] = __builtin_amdgcn_mfma_f32_16x16x32_bf16(qf0, kf0, s[ni], 0, 0, 0);
            s[ni] = __builtin_amdgcn_mfma_f32_16x16x32_bf16(qf1, kf1, s[ni], 0, 0, 0);
        }

        // online softmax; P -> Ps
        #pragma unroll
        for (int r = 0; r < 4; r++) {
            float s0 = s[0][r] * 0.125f, s1 = s[1][r] * 0.125f;
            float s2 = s[2][r] * 0.125f, s3 = s[3][r] * 0.125f;
            float tm = fmaxf(fmaxf(s0, s1), fmaxf(s2, s3));
            tm = fmaxf(tm, __shfl_xor(tm, 1));
            tm = fmaxf(tm, __shfl_xor(tm, 2));
            tm = fmaxf(tm, __shfl_xor(tm, 4));
            tm = fmaxf(tm, __shfl_xor(tm, 8));
            float mnew  = fmaxf(mrow[r], tm);
            float alpha = __expf(mrow[r] - mnew);
            mrow[r] = mnew;
            float p0 = __expf(s0 - mnew), p1 = __expf(s1 - mnew);
            float p2 = __expf(s2 - mnew), p3 = __expf(s3 - mnew);
            float ts = p0 + p1 + p2 + p3;
            ts += __shfl_xor(ts, 1);
            ts += __shfl_xor(ts, 2);
            ts += __shfl_xor(ts, 4);
            ts += __shfl_xor(ts, 8);
            lrow[r] = lrow[r] * alpha + ts;
            O[0][r] *= alpha; O[1][r] *= alpha; O[2][r] *= alpha; O[3][r] *= alpha;
            int qq = (w * 16 + quad * 4 + r) * 72 + lm;
            Ps[qq]      = f2bu(p0);
            Ps[qq + 16] = f2bu(p1);
            Ps[qq + 32] = f2bu(p2);
            Ps[qq + 48] = f2bu(p3);
        }
        __syncthreads();

        // O += P.V
        bf16x8 pf0 = *(const bf16x8*)&Ps[(w * 16 + lm) * 72 + quad * 8];
        bf16x8 pf1 = *(const bf16x8*)&Ps[(w * 16 + lm) * 72 + 32 + quad * 8];
        #pragma unroll
        for (int ni = 0; ni < 4; ni++) {
            bf16x8 vf0 = *(const bf16x8*)&Vs[(ni*16 + lm) * 72 + quad * 8];
            bf16x8 vf1 = *(const bf16x8*)&Vs[(ni*16 + lm) * 72 + 32 + quad * 8];
            O[ni] = __builtin_amdgcn_mfma_f32_16x16x32_bf16(pf0, vf0, O[ni], 0, 0, 0);
            O[ni] = __builtin_amdgcn_mfma_f32_16x16x32_bf16(pf1, vf1, O[ni], 0, 0, 0);
        }
        __syncthreads();   // Ks/Vs/Ps reuse next iter
    }

    // epilogue: normalize rows, bounce O through Ps [q][d], coalesced store
    #pragma unroll
    for (int r = 0; r < 4; r++) {
        float rinv = 1.f / lrow[r];
        int qq = (w * 16 + quad * 4 + r) * 72 + lm;
        Ps[qq]      = f2bu(O[0][r] * rinv);
        Ps[qq + 16] = f2bu(O[1][r] * rinv);
        Ps[qq + 32] = f2bu(O[2][r] * rinv);
        Ps[qq + 48] = f2bu(O[3][r] * rinv);
    }
    __syncthreads();
    {
        u16* dst = ao + ((size_t)b * PP + q0 + sr) * 512 + h * 64 + sc;
        *(uint4*)dst       = *(const uint4*)&Ps[sr * 72 + sc];
        *(uint4*)(dst + 8) = *(const uint4*)&Ps[sr * 72 + sc + 8];
    }
}

// ---------------------------------------------------------------------------
// Kernel 6: out-proj MFMA GEMM + bias + residual, f32 out (validated R6).
// ---------------------------------------------------------------------------
__launch_bounds__(256)
__global__ void mgemm_out_k(const u16* __restrict__ Wb, const float* __restrict__ bias,
                            const u16* __restrict__ actT, const float* __restrict__ resid,
                            float* __restrict__ out) {
    __shared__ __align__(16) u16 smem[10240];
    u16* As = smem;
    u16* Bs = smem + 5120;
    const int tid = threadIdx.x;
    const int p0 = blockIdx.x * 128;
    const int m0 = blockIdx.y * 128;
    const int b  = blockIdx.z;
    const int w = tid >> 6, l = tid & 63, quad = l >> 4, lm = l & 15;
    const int mo = (w >> 1) * 64, no = (w & 1) * 64;

    f32x4 acc[4][4] = {};

    const int srow = tid >> 1, sks = (tid & 1) << 4;
    const u16* wp = Wb + (size_t)(m0 + srow) * CCH + sks;
    const u16* ap = actT + (size_t)b * PP * CCH + (size_t)(p0 + srow) * CCH + sks;
    u16* asw = &As[srow * 40 + sks];
    u16* bsw = &Bs[srow * 40 + sks];

    for (int k0 = 0; k0 < CCH; k0 += 32) {
        uint4 aw0 = *(const uint4*)(wp + k0);
        uint4 aw1 = *(const uint4*)(wp + k0 + 8);
        uint4 bw0 = *(const uint4*)(ap + k0);
        uint4 bw1 = *(const uint4*)(ap + k0 + 8);
        *(uint4*)asw = aw0;  *(uint4*)(asw + 8) = aw1;
        *(uint4*)bsw = bw0;  *(uint4*)(bsw + 8) = bw1;
        __syncthreads();
        bf16x8 af[4], bfr[4];
        #pragma unroll
        for (int mi = 0; mi < 4; mi++)
            af[mi] = *(const bf16x8*)&As[(mo + mi*16 + lm) * 40 + quad * 8];
        #pragma unroll
        for (int ni = 0; ni < 4; ni++)
            bfr[ni] = *(const bf16x8*)&Bs[(no + ni*16 + lm) * 40 + quad * 8];
        #pragma unroll
        for (int mi = 0; mi < 4; mi++)
            #pragma unroll
            for (int ni = 0; ni < 4; ni++)
                acc[mi][ni] = __builtin_amdgcn_mfma_f32_16x16x32_bf16(
                    af[mi], bfr[ni], acc[mi][ni], 0, 0, 0);
        __syncthreads();
    }

    #pragma unroll
    for (int mi = 0; mi < 4; mi++) {
        f32x4 bv = *(const f32x4*)&bias[m0 + mo + mi*16 + quad*4];
        #pragma unroll
        for (int ni = 0; ni < 4; ni++) {
            int p = p0 + no + ni*16 + lm;
            #pragma unroll
            for (int r = 0; r < 4; r++) {
                int m = m0 + mo + mi*16 + quad*4 + r;
                size_t idx = ((size_t)b * CCH + m) * PP + p;
                out[idx] = acc[mi][ni][r] + bv[r] + resid[idx];
            }
        }
    }
}

// ---------------------------------------------------------------------------
extern "C" void kernel_launch(void* const* d_in, const int* in_sizes, int n_in,
                              void* d_out, int out_size, void* d_ws, size_t ws_size,
                              hipStream_t stream) {
    const float* x     = (const float*)d_in[0];
    const float* gamma = (const float*)d_in[1];
    const float* beta  = (const float*)d_in[2];
    const float* w_qkv = (const float*)d_in[3];
    const float* b_qkv = (const float*)d_in[4];
    const float* w_out = (const float*)d_in[5];
    const float* b_out = (const float*)d_in[6];

    char* ws = (char*)d_ws;
    float* mean = (float*)ws;                   // 128 f32
    float* rstd = (float*)(ws + 1024);          // 128 f32
    u16* wqb = (u16*)(ws + 4096);               // 1536*512
    u16* wob = wqb + 1536 * 512;                // 512*512
    u16* xbt = wob + 512 * 512;                 // [b][p][c]  8.4M elems
    u16* ao  = xbt + (size_t)BB * PP * CCH;     // [b][p][c]  8.4M
    u16* qTb = ao  + (size_t)BB * PP * CCH;     // [b][p][512] 8.4M
    u16* kTb = qTb + (size_t)BB * PP * CCH;     // [b][p][512] 8.4M
    u16* vb  = kTb + (size_t)BB * PP * CCH;     // [b][512][p] 8.4M  (~86 MB)

    gn_stats_k<<<128, 256, 0, stream>>>(x, mean, rstd);
    conv_x_k<<<dim3(16, 8, 16), 256, 0, stream>>>(x, mean, rstd, gamma, beta, xbt);
    conv_w_k<<<1024, 256, 0, stream>>>(w_qkv, w_out, wqb, wob);
    mgemm_qkv_k<<<dim3(8, 12, 16), 256, 0, stream>>>(wqb, b_qkv, xbt, qTb, kTb, vb);
    fattn_k<<<dim3(16, 8, 16), 256, 0, stream>>>(qTb, kTb, vb, ao);
    mgemm_out_k<<<dim3(8, 4, 16), 256, 0, stream>>>(wob, b_out, ao, x, (float*)d_out);
}

// Round 9
// 311.632 us; speedup vs baseline: 11.1584x; 1.0531x over previous
//
#include <hip/hip_runtime.h>
#include <hip/hip_bf16.h>

// B=16, C=512, H=W=32 -> P=1024 pixels, 8 groups (64 ch), 8 heads (hd=64).
// Inputs f32, output f32.  Internals bf16 + fp32 accum (validated R6/R8).
#define BB   16
#define CCH  512
#define PP   1024
#define NHD  8

typedef unsigned short u16;
typedef unsigned int   u32;
typedef __attribute__((ext_vector_type(8))) short bf16x8;   // 8 bf16 = 4 VGPR
typedef __attribute__((ext_vector_type(4))) float f32x4;

__device__ __forceinline__ float us2f(u16 u) {
    return __uint_as_float(((u32)u) << 16);
}
__device__ __forceinline__ u16 f2bu(float f) {
    __hip_bfloat16 h = __float2bfloat16(f);   // RNE
    return *reinterpret_cast<u16*>(&h);
}

// ---------------------------------------------------------------------------
// Kernel 1: per-(batch,group) mean / rstd.  128 blocks x 1024 threads.
// ---------------------------------------------------------------------------
__launch_bounds__(1024)
__global__ void gn_stats_k(const float* __restrict__ x,
                           float* __restrict__ mean, float* __restrict__ rstd) {
    int bg = blockIdx.x;
    const float4* xp = (const float4*)(x + (size_t)bg * 65536);
    float s = 0.f, ss = 0.f;
    for (int i = threadIdx.x; i < 16384; i += 1024) {
        float4 v = xp[i];
        s  += v.x + v.y + v.z + v.w;
        ss += v.x*v.x + v.y*v.y + v.z*v.z + v.w*v.w;
    }
    __shared__ float sh[1024], sq[1024];
    sh[threadIdx.x] = s; sq[threadIdx.x] = ss;
    __syncthreads();
    for (int off = 512; off > 0; off >>= 1) {
        if (threadIdx.x < off) {
            sh[threadIdx.x] += sh[threadIdx.x + off];
            sq[threadIdx.x] += sq[threadIdx.x + off];
        }
        __syncthreads();
    }
    if (threadIdx.x == 0) {
        float m   = sh[0] * (1.f / 65536.f);
        float var = sq[0] * (1.f / 65536.f) - m * m;
        mean[bg] = m;
        rstd[bg] = rsqrtf(var + 1e-5f);
    }
}

// ---------------------------------------------------------------------------
// Kernel 2: GN-normalize + convert + transpose: x[b][c][p] f32 ->
// xbt[b][p][c] bf16.
// ---------------------------------------------------------------------------
__launch_bounds__(256)
__global__ void conv_x_k(const float* __restrict__ x,
                         const float* __restrict__ mean, const float* __restrict__ rstd,
                         const float* __restrict__ gamma, const float* __restrict__ beta,
                         u16* __restrict__ xbt) {
    __shared__ u16 T[64][73];
    const int tid = threadIdx.x;
    const int p0 = blockIdx.x * 64;
    const int c0 = blockIdx.y * 64;
    const int b  = blockIdx.z;
    {
        int ci = tid >> 2, ps = (tid & 3) * 16;
        int c = c0 + ci;
        int bg = (b << 3) + (c >> 6);
        float sc = rstd[bg] * gamma[c];
        float sf = beta[c] - mean[bg] * sc;
        const float* xp = x + ((size_t)(b * CCH + c)) * PP + p0 + ps;
        #pragma unroll
        for (int j4 = 0; j4 < 4; j4++) {
            float4 v = *(const float4*)(xp + j4 * 4);
            T[ps + j4*4 + 0][ci] = f2bu(v.x * sc + sf);
            T[ps + j4*4 + 1][ci] = f2bu(v.y * sc + sf);
            T[ps + j4*4 + 2][ci] = f2bu(v.z * sc + sf);
            T[ps + j4*4 + 3][ci] = f2bu(v.w * sc + sf);
        }
    }
    __syncthreads();
    {
        int pi = tid >> 2, cs = (tid & 3) * 16;
        u16* dst = xbt + ((size_t)(b * PP) + p0 + pi) * CCH + c0 + cs;
        #pragma unroll
        for (int j4 = 0; j4 < 4; j4++) {
            ushort4 o;
            o.x = T[pi][cs + j4*4 + 0]; o.y = T[pi][cs + j4*4 + 1];
            o.z = T[pi][cs + j4*4 + 2]; o.w = T[pi][cs + j4*4 + 3];
            *(ushort4*)(dst + j4 * 4) = o;
        }
    }
}

// ---------------------------------------------------------------------------
// Kernel 3: weights f32 -> bf16.
// ---------------------------------------------------------------------------
__launch_bounds__(256)
__global__ void conv_w_k(const float* __restrict__ w1, const float* __restrict__ w2,
                         u16* __restrict__ d1, u16* __restrict__ d2) {
    int id = blockIdx.x * 256 + threadIdx.x;
    const float* s; u16* d; int off;
    if (id < 196608) { s = w1; d = d1; off = id * 4; }
    else             { s = w2; d = d2; off = (id - 196608) * 4; }
    float4 v = *(const float4*)(s + off);
    ushort4 o;
    o.x = f2bu(v.x); o.y = f2bu(v.y); o.z = f2bu(v.z); o.w = f2bu(v.w);
    *(ushort4*)(d + off) = o;
}

// ---------------------------------------------------------------------------
// Kernel 4: qkv MFMA GEMM (unchanged from passing R8).
// ---------------------------------------------------------------------------
__launch_bounds__(256)
__global__ void mgemm_qkv_k(const u16* __restrict__ Wb, const float* __restrict__ bias,
                            const u16* __restrict__ actT,
                            u16* __restrict__ qT, u16* __restrict__ kT,
                            u16* __restrict__ v) {
    __shared__ __align__(16) u16 smem[17408];    // staging 2x5120 | Cb 128x136
    u16* As = smem;                              // [128][40]
    u16* Bs = smem + 5120;                       // [128][40]
    const int tid = threadIdx.x;
    const int p0 = blockIdx.x * 128;
    const int m0 = blockIdx.y * 128;
    const int b  = blockIdx.z;
    const int w = tid >> 6, l = tid & 63, quad = l >> 4, lm = l & 15;
    const int mo = (w >> 1) * 64, no = (w & 1) * 64;

    f32x4 acc[4][4] = {};

    const int srow = tid >> 1, sks = (tid & 1) << 4;
    const u16* wp = Wb + (size_t)(m0 + srow) * CCH + sks;
    const u16* ap = actT + (size_t)b * PP * CCH + (size_t)(p0 + srow) * CCH + sks;
    u16* asw = &As[srow * 40 + sks];
    u16* bsw = &Bs[srow * 40 + sks];

    for (int k0 = 0; k0 < CCH; k0 += 32) {
        uint4 aw0 = *(const uint4*)(wp + k0);
        uint4 aw1 = *(const uint4*)(wp + k0 + 8);
        uint4 bw0 = *(const uint4*)(ap + k0);
        uint4 bw1 = *(const uint4*)(ap + k0 + 8);
        *(uint4*)asw = aw0;  *(uint4*)(asw + 8) = aw1;
        *(uint4*)bsw = bw0;  *(uint4*)(bsw + 8) = bw1;
        __syncthreads();
        bf16x8 af[4], bfr[4];
        #pragma unroll
        for (int mi = 0; mi < 4; mi++)
            af[mi] = *(const bf16x8*)&As[(mo + mi*16 + lm) * 40 + quad * 8];
        #pragma unroll
        for (int ni = 0; ni < 4; ni++)
            bfr[ni] = *(const bf16x8*)&Bs[(no + ni*16 + lm) * 40 + quad * 8];
        #pragma unroll
        for (int mi = 0; mi < 4; mi++)
            #pragma unroll
            for (int ni = 0; ni < 4; ni++)
                acc[mi][ni] = __builtin_amdgcn_mfma_f32_16x16x32_bf16(
                    af[mi], bfr[ni], acc[mi][ni], 0, 0, 0);
        __syncthreads();
    }

    const int region = m0 >> 9;   // 0=Q 1=K 2=V
    if (region < 2) {
        u16* Cb = smem;
        #pragma unroll
        for (int mi = 0; mi < 4; mi++) {
            f32x4 bv = *(const f32x4*)&bias[m0 + mo + mi*16 + quad*4];
            #pragma unroll
            for (int ni = 0; ni < 4; ni++) {
                int colp = no + ni*16 + lm;
                int rowb = mo + mi*16 + quad*4;
                #pragma unroll
                for (int r = 0; r < 4; r++)
                    Cb[colp * 136 + rowb + r] = f2bu(acc[mi][ni][r] + bv[r]);
            }
        }
        __syncthreads();
        int prow = tid >> 1, half = tid & 1;
        u16* base = (region == 0) ? qT : kT;
        u16* dst = base + ((size_t)b * PP + p0 + prow) * 512 + (m0 & 511) + half * 64;
        const u16* src = &Cb[prow * 136 + half * 64];
        #pragma unroll
        for (int i = 0; i < 8; i++)
            *(uint4*)(dst + i * 8) = *(const uint4*)(src + i * 8);
    } else {
        u16* Cb = smem;
        #pragma unroll
        for (int mi = 0; mi < 4; mi++) {
            f32x4 bv = *(const f32x4*)&bias[m0 + mo + mi*16 + quad*4];
            #pragma unroll
            for (int ni = 0; ni < 4; ni++) {
                int colp = no + ni*16 + lm;
                int rowb = mo + mi*16 + quad*4;
                #pragma unroll
                for (int r = 0; r < 4; r++)
                    Cb[(rowb + r) * 136 + colp] = f2bu(acc[mi][ni][r] + bv[r]);
            }
        }
        __syncthreads();
        int row = tid >> 1, half = tid & 1;
        u16* dst = v + ((size_t)b * 512 + (m0 - 1024) + row) * PP + p0 + half * 64;
        const u16* src = &Cb[row * 136 + half * 64];
        #pragma unroll
        for (int i = 0; i < 8; i++)
            *(uint4*)(dst + i * 8) = *(const uint4*)(src + i * 8);
    }
}

// ---------------------------------------------------------------------------
// Kernel 5: MFMA flash attention, j-tile 128, 2 barriers/iter.
// Block = (b, h, 64-q tile), 4 waves; wave w owns q rows w*16..w*16+15.
// Wave-locality: Q staging, P C->A round-trip, and epilogue all touch only
// wave-w rows of Ps, and DS ops complete in-order per wave -> NO barrier.
// Barriers only around K/V staging (cross-wave).
//   Ps [64][136] u16 : Q staging -> P -> O out      (17408 B)
//   Ks [128][72] u16 : K tile [j][d]                (18432 B)
//   Vs [64][136] u16 : V tile [d][j]                (17408 B)   total 53 KB
// ---------------------------------------------------------------------------
__launch_bounds__(256)
__global__ void fattn_k(const u16* __restrict__ qT, const u16* __restrict__ kT,
                        const u16* __restrict__ v, u16* __restrict__ ao) {
    __shared__ __align__(16) u16 Ps[64 * 136];
    __shared__ __align__(16) u16 Ks[128 * 72];
    __shared__ __align__(16) u16 Vs[64 * 136];
    const int tid = threadIdx.x;
    const int q0 = blockIdx.x * 64;
    const int h  = blockIdx.y;
    const int b  = blockIdx.z;
    const int w = tid >> 6, l = tid & 63, quad = l >> 4, lm = l & 15;

    // stage Q (wave-local rows): lane -> row w*16+(l>>2), 16-u16 chunk (l&3)
    {
        int r = w * 16 + (l >> 2), c = (l & 3) * 16;
        const u16* src = qT + ((size_t)b * PP + q0 + r) * 512 + h * 64 + c;
        *(uint4*)&Ps[r * 136 + c]     = *(const uint4*)src;
        *(uint4*)&Ps[r * 136 + c + 8] = *(const uint4*)(src + 8);
    }
    // wave-local read-after-write: DS in-order per wave, no barrier
    bf16x8 qf0 = *(const bf16x8*)&Ps[(w * 16 + lm) * 136 + quad * 8];
    bf16x8 qf1 = *(const bf16x8*)&Ps[(w * 16 + lm) * 136 + 32 + quad * 8];

    f32x4 O[4] = {};
    float mrow[4] = {-3.0e38f, -3.0e38f, -3.0e38f, -3.0e38f};
    float lrow[4] = {};

    const int ksr = tid >> 1, ksc = (tid & 1) * 32;   // Ks: 2 thr/row, 32 u16
    const int vsr = tid >> 2, vsc = (tid & 3) * 32;   // Vs: 4 thr/row, 32 u16

    for (int j0 = 0; j0 < PP; j0 += 128) {
        __syncthreads();   // previous iter's Ks/Vs reads done
        {
            const u16* ksrc = kT + ((size_t)b * PP + j0 + ksr) * 512 + h * 64 + ksc;
            *(uint4*)&Ks[ksr * 72 + ksc]      = *(const uint4*)ksrc;
            *(uint4*)&Ks[ksr * 72 + ksc + 8]  = *(const uint4*)(ksrc + 8);
            *(uint4*)&Ks[ksr * 72 + ksc + 16] = *(const uint4*)(ksrc + 16);
            *(uint4*)&Ks[ksr * 72 + ksc + 24] = *(const uint4*)(ksrc + 24);
            const u16* vsrc = v + ((size_t)b * 512 + h * 64 + vsr) * PP + j0 + vsc;
            *(uint4*)&Vs[vsr * 136 + vsc]      = *(const uint4*)vsrc;
            *(uint4*)&Vs[vsr * 136 + vsc + 8]  = *(const uint4*)(vsrc + 8);
            *(uint4*)&Vs[vsr * 136 + vsc + 16] = *(const uint4*)(vsrc + 16);
            *(uint4*)&Vs[vsr * 136 + vsc + 24] = *(const uint4*)(vsrc + 24);
        }
        __syncthreads();   // staging visible to all waves

        // S = Q.K^T : 8 j-subtiles x (k=64 -> 2 MFMAs)
        f32x4 s[8];
        #pragma unroll
        for (int ni = 0; ni < 8; ni++) {
            bf16x8 kf0 = *(const bf16x8*)&Ks[(ni*16 + lm) * 72 + quad * 8];
            bf16x8 kf1 = *(const bf16x8*)&Ks[(ni*16 + lm) * 72 + 32 + quad * 8];
            f32x4 z = {};
            z = __builtin_amdgcn_mfma_f32_16x16x32_bf16(qf0, kf0, z, 0, 0, 0);
            s[ni] = __builtin_amdgcn_mfma_f32_16x16x32_bf16(qf1, kf1, z, 0, 0, 0);
        }

        // online softmax (row = 16 lanes lm of this quad); P -> Ps (wave-local)
        #pragma unroll
        for (int r = 0; r < 4; r++) {
            float e[8];
            #pragma unroll
            for (int ni = 0; ni < 8; ni++) e[ni] = s[ni][r] * 0.125f;
            float tm = fmaxf(fmaxf(fmaxf(e[0], e[1]), fmaxf(e[2], e[3])),
                             fmaxf(fmaxf(e[4], e[5]), fmaxf(e[6], e[7])));
            tm = fmaxf(tm, __shfl_xor(tm, 1));
            tm = fmaxf(tm, __shfl_xor(tm, 2));
            tm = fmaxf(tm, __shfl_xor(tm, 4));
            tm = fmaxf(tm, __shfl_xor(tm, 8));
            float mnew  = fmaxf(mrow[r], tm);
            float alpha = __expf(mrow[r] - mnew);
            mrow[r] = mnew;
            float ts = 0.f;
            int qq = (w * 16 + quad * 4 + r) * 136 + lm;
            #pragma unroll
            for (int ni = 0; ni < 8; ni++) {
                float p = __expf(e[ni] - mnew);
                ts += p;
                Ps[qq + ni * 16] = f2bu(p);
            }
            ts += __shfl_xor(ts, 1);
            ts += __shfl_xor(ts, 2);
            ts += __shfl_xor(ts, 4);
            ts += __shfl_xor(ts, 8);
            lrow[r] = lrow[r] * alpha + ts;
            O[0][r] *= alpha; O[1][r] *= alpha; O[2][r] *= alpha; O[3][r] *= alpha;
        }
        // no barrier: P write/read is wave-local, DS in-order

        // O += P.V : 4 k-frags (j) x 4 d-subtiles
        #pragma unroll
        for (int kf = 0; kf < 4; kf++) {
            bf16x8 pf = *(const bf16x8*)&Ps[(w*16 + lm) * 136 + kf * 32 + quad * 8];
            #pragma unroll
            for (int nd = 0; nd < 4; nd++) {
                bf16x8 vf = *(const bf16x8*)&Vs[(nd*16 + lm) * 136 + kf * 32 + quad * 8];
                O[nd] = __builtin_amdgcn_mfma_f32_16x16x32_bf16(pf, vf, O[nd], 0, 0, 0);
            }
        }
    }

    // epilogue (wave-local): normalize, O -> Ps [q][d], coalesced store
    #pragma unroll
    for (int r = 0; r < 4; r++) {
        float rinv = 1.f / lrow[r];
        int qq = (w * 16 + quad * 4 + r) * 136 + lm;
        Ps[qq]      = f2bu(O[0][r] * rinv);
        Ps[qq + 16] = f2bu(O[1][r] * rinv);
        Ps[qq + 32] = f2bu(O[2][r] * rinv);
        Ps[qq + 48] = f2bu(O[3][r] * rinv);
    }
    {
        int r = w * 16 + (l >> 2), c = (l & 3) * 16;
        u16* dst = ao + ((size_t)b * PP + q0 + r) * 512 + h * 64 + c;
        *(uint4*)dst       = *(const uint4*)&Ps[r * 136 + c];
        *(uint4*)(dst + 8) = *(const uint4*)&Ps[r * 136 + c + 8];
    }
}

// ---------------------------------------------------------------------------
// Kernel 6: out-proj MFMA GEMM + bias + residual, f32 out (unchanged R8).
// ---------------------------------------------------------------------------
__launch_bounds__(256)
__global__ void mgemm_out_k(const u16* __restrict__ Wb, const float* __restrict__ bias,
                            const u16* __restrict__ actT, const float* __restrict__ resid,
                            float* __restrict__ out) {
    __shared__ __align__(16) u16 smem[10240];
    u16* As = smem;
    u16* Bs = smem + 5120;
    const int tid = threadIdx.x;
    const int p0 = blockIdx.x * 128;
    const int m0 = blockIdx.y * 128;
    const int b  = blockIdx.z;
    const int w = tid >> 6, l = tid & 63, quad = l >> 4, lm = l & 15;
    const int mo = (w >> 1) * 64, no = (w & 1) * 64;

    f32x4 acc[4][4] = {};

    const int srow = tid >> 1, sks = (tid & 1) << 4;
    const u16* wp = Wb + (size_t)(m0 + srow) * CCH + sks;
    const u16* ap = actT + (size_t)b * PP * CCH + (size_t)(p0 + srow) * CCH + sks;
    u16* asw = &As[srow * 40 + sks];
    u16* bsw = &Bs[srow * 40 + sks];

    for (int k0 = 0; k0 < CCH; k0 += 32) {
        uint4 aw0 = *(const uint4*)(wp + k0);
        uint4 aw1 = *(const uint4*)(wp + k0 + 8);
        uint4 bw0 = *(const uint4*)(ap + k0);
        uint4 bw1 = *(const uint4*)(ap + k0 + 8);
        *(uint4*)asw = aw0;  *(uint4*)(asw + 8) = aw1;
        *(uint4*)bsw = bw0;  *(uint4*)(bsw + 8) = bw1;
        __syncthreads();
        bf16x8 af[4], bfr[4];
        #pragma unroll
        for (int mi = 0; mi < 4; mi++)
            af[mi] = *(const bf16x8*)&As[(mo + mi*16 + lm) * 40 + quad * 8];
        #pragma unroll
        for (int ni = 0; ni < 4; ni++)
            bfr[ni] = *(const bf16x8*)&Bs[(no + ni*16 + lm) * 40 + quad * 8];
        #pragma unroll
        for (int mi = 0; mi < 4; mi++)
            #pragma unroll
            for (int ni = 0; ni < 4; ni++)
                acc[mi][ni] = __builtin_amdgcn_mfma_f32_16x16x32_bf16(
                    af[mi], bfr[ni], acc[mi][ni], 0, 0, 0);
        __syncthreads();
    }

    #pragma unroll
    for (int mi = 0; mi < 4; mi++) {
        f32x4 bv = *(const f32x4*)&bias[m0 + mo + mi*16 + quad*4];
        #pragma unroll
        for (int ni = 0; ni < 4; ni++) {
            int p = p0 + no + ni*16 + lm;
            #pragma unroll
            for (int r = 0; r < 4; r++) {
                int m = m0 + mo + mi*16 + quad*4 + r;
                size_t idx = ((size_t)b * CCH + m) * PP + p;
                out[idx] = acc[mi][ni][r] + bv[r] + resid[idx];
            }
        }
    }
}

// ---------------------------------------------------------------------------
extern "C" void kernel_launch(void* const* d_in, const int* in_sizes, int n_in,
                              void* d_out, int out_size, void* d_ws, size_t ws_size,
                              hipStream_t stream) {
    const float* x     = (const float*)d_in[0];
    const float* gamma = (const float*)d_in[1];
    const float* beta  = (const float*)d_in[2];
    const float* w_qkv = (const float*)d_in[3];
    const float* b_qkv = (const float*)d_in[4];
    const float* w_out = (const float*)d_in[5];
    const float* b_out = (const float*)d_in[6];

    char* ws = (char*)d_ws;
    float* mean = (float*)ws;                   // 128 f32
    float* rstd = (float*)(ws + 1024);          // 128 f32
    u16* wqb = (u16*)(ws + 4096);               // 1536*512
    u16* wob = wqb + 1536 * 512;                // 512*512
    u16* xbt = wob + 512 * 512;                 // [b][p][c]  8.4M elems
    u16* ao  = xbt + (size_t)BB * PP * CCH;     // [b][p][c]  8.4M
    u16* qTb = ao  + (size_t)BB * PP * CCH;     // [b][p][512] 8.4M
    u16* kTb = qTb + (size_t)BB * PP * CCH;     // [b][p][512] 8.4M
    u16* vb  = kTb + (size_t)BB * PP * CCH;     // [b][512][p] 8.4M  (~86 MB)

    gn_stats_k<<<128, 1024, 0, stream>>>(x, mean, rstd);
    conv_x_k<<<dim3(16, 8, 16), 256, 0, stream>>>(x, mean, rstd, gamma, beta, xbt);
    conv_w_k<<<1024, 256, 0, stream>>>(w_qkv, w_out, wqb, wob);
    mgemm_qkv_k<<<dim3(8, 12, 16), 256, 0, stream>>>(wqb, b_qkv, xbt, qTb, kTb, vb);
    fattn_k<<<dim3(16, 8, 16), 256, 0, stream>>>(qTb, kTb, vb, ao);
    mgemm_out_k<<<dim3(8, 4, 16), 256, 0, stream>>>(wob, b_out, ao, x, (float*)d_out);
}